// Round 1
// 1394.923 us; speedup vs baseline: 1.1569x; 1.1569x over previous
//
#include <hip/hip_runtime.h>

#define N_NODES 100000
#define N_EDGES 200000
#define IN_FEATS 1024
#define H_FEATS 512
#define N_HEADS 4
#define HEAD_DIM 128
#define N_CLASSES 2983
#define BATCH 1024

typedef __attribute__((ext_vector_type(8))) short short8;
typedef __attribute__((ext_vector_type(4))) float floatx4;

typedef __attribute__((address_space(1))) void global_as_void;
typedef __attribute__((address_space(3))) void lds_as_void;

__device__ __forceinline__ float bf2f(unsigned short u) {
    union { unsigned int i; float f; } x; x.i = ((unsigned int)u) << 16; return x.f;
}
__device__ __forceinline__ unsigned short f2bf(float f) {
    union { float f; unsigned int i; } x; x.f = f;
    unsigned int r = x.i + 0x7FFFu + ((x.i >> 16) & 1u);
    return (unsigned short)(r >> 16);
}
__device__ __forceinline__ void load_lds16(const void* g, void* l) {
    __builtin_amdgcn_global_load_lds((const global_as_void*)g, (lds_as_void*)l, 16, 0, 0);
}

// ---------------- GEMM ----------------
// C[M,N] = A([M,K] bf16, or fp32 if a_fp32) @ BT(bf16 [N,K])^T
// 1D grid, n-tile fastest (A-tile L2 reuse). Optional row indirection:
//   countp: device count of valid rows (null -> M); rowlist: compacted row->node
//   map (null -> identity). A reads, C stores, att atomics all go through it.
// att epilogue: head h = n_tile (0..7); h<4 uses att_s/att_d, h>=4 uses
//   att_s2/att_d2 (head h&3); logits atomicAdd'ed at node*8 + h.
// LDS layout swizzle: 16B slot c of row r holds global k-chunk c ^ ((r>>1)&3).
__global__ __launch_bounds__(256, 3)
void gemm_kernel(const void* __restrict__ Ain, int a_fp32,
                 const unsigned short* __restrict__ BT,
                 void* __restrict__ Cout, const float* __restrict__ bias,
                 const float* __restrict__ att_s, const float* __restrict__ att_d,
                 const float* __restrict__ att_s2, const float* __restrict__ att_d2,
                 float* __restrict__ asrc, float* __restrict__ adst,
                 const int* __restrict__ rowlist, const int* __restrict__ countp,
                 int M, int N, int n_tiles, int K, int out_bf16)
{
    __shared__ __attribute__((aligned(16))) unsigned short As[128 * 32];
    __shared__ __attribute__((aligned(16))) unsigned short Bs[128 * 32];
    const int tid  = threadIdx.x;
    const int lane = tid & 63;
    const int wave = tid >> 6;
    const int bid = blockIdx.x;
    const int mt = bid / n_tiles;
    const int nt = bid - mt * n_tiles;
    const int m0 = mt * 128;
    const int n0 = nt * 128;
    int Mv = M;
    if (countp) Mv = countp[0];
    if (m0 >= Mv) return;           // uniform across block: safe before barriers
    const int wr = (wave >> 1) * 64;
    const int wc = (wave & 1) * 64;
    const int lm = lane & 15;
    const int quad = lane >> 4;

    auto arow = [&](int r) -> int {
        int gr = m0 + r; if (gr > Mv - 1) gr = Mv - 1;
        if (rowlist) gr = rowlist[gr];
        return gr;
    };

    floatx4 acc[4][4];
#pragma unroll
    for (int i = 0; i < 4; i++)
#pragma unroll
        for (int j = 0; j < 4; j++) acc[i][j] = (floatx4)0.0f;

    for (int k0 = 0; k0 < K; k0 += 32) {
        __syncthreads();
        if (a_fp32) {
            // VALU staging: fp32 -> bf16, same swizzled layout
            int row = tid >> 2;
            int slot = tid & 3;
#pragma unroll
            for (int p = 0; p < 2; p++) {
                int r = p * 64 + row;
                int gr = arow(r);
                int gc = (slot ^ ((r >> 1) & 3)) * 8;
                const float* ap = (const float*)Ain + (size_t)gr * K + k0 + gc;
                floatx4 f0 = *(const floatx4*)ap;
                floatx4 f1 = *(const floatx4*)(ap + 4);
                short8 v;
                v[0] = (short)f2bf(f0[0]); v[1] = (short)f2bf(f0[1]);
                v[2] = (short)f2bf(f0[2]); v[3] = (short)f2bf(f0[3]);
                v[4] = (short)f2bf(f1[0]); v[5] = (short)f2bf(f1[1]);
                v[6] = (short)f2bf(f1[2]); v[7] = (short)f2bf(f1[3]);
                *(short8*)&As[r * 32 + slot * 8] = v;
            }
        } else {
            // direct global->LDS DMA, 16B/lane; dest = wave-uniform base + lane*16
#pragma unroll
            for (int i = 0; i < 2; i++) {
                int r = wave * 32 + i * 16 + (lane >> 2);
                int gr = arow(r);
                int gc = ((lane & 3) ^ ((r >> 1) & 3)) * 8;
                load_lds16((const unsigned short*)Ain + (size_t)gr * K + k0 + gc,
                           (char*)As + (size_t)(wave * 2 + i) * 1024);
            }
        }
#pragma unroll
        for (int i = 0; i < 2; i++) {
            int r = wave * 32 + i * 16 + (lane >> 2);
            int gn = n0 + r; if (gn > N - 1) gn = N - 1;
            int gc = ((lane & 3) ^ ((r >> 1) & 3)) * 8;
            load_lds16(BT + (size_t)gn * K + k0 + gc,
                       (char*)Bs + (size_t)(wave * 2 + i) * 1024);
        }
        __syncthreads();
        short8 af[4], bfr[4];
#pragma unroll
        for (int i = 0; i < 4; i++) {
            int ra = wr + i * 16 + lm;
            af[i] = *(const short8*)&As[ra * 32 + ((quad ^ ((ra >> 1) & 3)) << 3)];
            int rb = wc + i * 16 + lm;
            bfr[i] = *(const short8*)&Bs[rb * 32 + ((quad ^ ((rb >> 1) & 3)) << 3)];
        }
#pragma unroll
        for (int i = 0; i < 4; i++)
#pragma unroll
            for (int j = 0; j < 4; j++)
                acc[i][j] = __builtin_amdgcn_mfma_f32_16x16x32_bf16(af[i], bfr[j], acc[i][j], 0, 0, 0);
    }

    // fused attention logits (this block covers exactly one head's 128 cols)
    if (att_s) {
        const int h = n0 >> 7;
        const float* wsp = (h < 4) ? att_s : att_s2;
        const float* wdp = (h < 4) ? att_d : att_d2;
        const int hh = h & 3;
#pragma unroll
        for (int i = 0; i < 4; i++) {
#pragma unroll
            for (int r = 0; r < 4; r++) {
                float ss = 0.f, sd = 0.f;
#pragma unroll
                for (int j = 0; j < 4; j++) {
                    int c = wc + j * 16 + lm;
                    ss += acc[i][j][r] * wsp[hh * HEAD_DIM + c];
                    sd += acc[i][j][r] * wdp[hh * HEAD_DIM + c];
                }
#pragma unroll
                for (int off = 1; off < 16; off <<= 1) {
                    ss += __shfl_xor(ss, off);
                    sd += __shfl_xor(sd, off);
                }
                int grl = m0 + wr + i * 16 + quad * 4 + r;
                if (lm == 0 && grl < Mv) {
                    int gr = rowlist ? rowlist[grl] : grl;
                    atomicAdd(&asrc[(size_t)gr * 8 + h], ss);
                    atomicAdd(&adst[(size_t)gr * 8 + h], sd);
                }
            }
        }
    }

    // C store: C/D layout col=lane&15, row=quad*4+reg
#pragma unroll
    for (int i = 0; i < 4; i++) {
        int grb = wr + i * 16 + quad * 4;
#pragma unroll
        for (int j = 0; j < 4; j++) {
            int gc = n0 + wc + j * 16 + lm;
            if (gc < N) {
#pragma unroll
                for (int r = 0; r < 4; r++) {
                    int grl = m0 + grb + r;
                    if (grl < Mv) {
                        int gr = rowlist ? rowlist[grl] : grl;
                        float v = acc[i][j][r];
                        if (out_bf16) {
                            ((unsigned short*)Cout)[(size_t)gr * N + gc] = f2bf(v);
                        } else {
                            float b = bias ? bias[gc] : 0.0f;
                            ((float*)Cout)[(size_t)gr * N + gc] = v + b;
                        }
                    }
                }
            }
        }
    }
}

// ---------------- fp32 -> bf16 bulk convert ----------------
__global__ void cvt_bf16_kernel(const float* __restrict__ X, unsigned short* __restrict__ Y, int n8)
{
    int i = blockIdx.x * blockDim.x + threadIdx.x;
    if (i >= n8) return;
    const floatx4* xp = (const floatx4*)X + (size_t)i * 2;
    floatx4 f0 = xp[0], f1 = xp[1];
    short8 v;
    v[0] = (short)f2bf(f0[0]); v[1] = (short)f2bf(f0[1]);
    v[2] = (short)f2bf(f0[2]); v[3] = (short)f2bf(f0[3]);
    v[4] = (short)f2bf(f1[0]); v[5] = (short)f2bf(f1[1]);
    v[6] = (short)f2bf(f1[2]); v[7] = (short)f2bf(f1[3]);
    *(short8*)(Y + (size_t)i * 8) = v;
}

// ---------------- CSR build ----------------
__global__ void hist_kernel(const int* __restrict__ dst, int* __restrict__ cnt, int E)
{
    int e = blockIdx.x * blockDim.x + threadIdx.x;
    if (e < E) atomicAdd(&cnt[dst[e]], 1);
}

__global__ void scan1_kernel(const int* __restrict__ cnt, int* __restrict__ partial,
                             int* __restrict__ chunksum, int n)
{
    __shared__ int sm[256];
    int t = threadIdx.x;
    int i = blockIdx.x * 256 + t;
    int v = (i < n) ? cnt[i] : 0;
    sm[t] = v; __syncthreads();
    int val = v;
#pragma unroll
    for (int off = 1; off < 256; off <<= 1) {
        int u = (t >= off) ? sm[t - off] : 0;
        __syncthreads();
        val += u; sm[t] = val;
        __syncthreads();
    }
    if (i < n) partial[i] = val - v;
    if (t == 255) chunksum[blockIdx.x] = val;
}

__global__ void scan2_kernel(int* __restrict__ chunksum, int n)
{
    __shared__ int sm[512];
    int t = threadIdx.x;
    int v = (t < n) ? chunksum[t] : 0;
    sm[t] = v; __syncthreads();
    int val = v;
#pragma unroll
    for (int off = 1; off < 512; off <<= 1) {
        int u = (t >= off) ? sm[t - off] : 0;
        __syncthreads();
        val += u; sm[t] = val;
        __syncthreads();
    }
    if (t < n) chunksum[t] = val - v;
}

__global__ void scan3_kernel(const int* __restrict__ partial, const int* __restrict__ chunksum,
                             int* __restrict__ rowptr, int* __restrict__ cursor, int n, int E)
{
    int i = blockIdx.x * 256 + threadIdx.x;
    if (i < n) {
        int r = partial[i] + chunksum[i >> 8];
        rowptr[i] = r;
        cursor[i] = r;
    }
    if (i == 0) rowptr[n] = E;
}

__global__ void fill_kernel(const int* __restrict__ src, const int* __restrict__ dst,
                            int* __restrict__ cursor, int* __restrict__ srcs_sorted, int E)
{
    int e = blockIdx.x * blockDim.x + threadIdx.x;
    if (e < E) {
        int p = atomicAdd(&cursor[dst[e]], 1);
        srcs_sorted[p] = src[e];
    }
}

// ---------------- layer-1 needed-node marking / compaction ----------------
// flag nodes needed by layer 1: sources of edges with dst < BATCH (both types)
// plus the BATCH dst nodes themselves.
__global__ void mark_kernel(const int* __restrict__ rowptr1, const int* __restrict__ srcs1,
                            const int* __restrict__ rowptr2, const int* __restrict__ srcs2,
                            int* __restrict__ flag, int E)
{
    int e = blockIdx.x * blockDim.x + threadIdx.x;
    if (e >= E) return;
    if (e < BATCH) flag[e] = 1;
    if (e < rowptr1[BATCH]) flag[srcs1[e]] = 1;
    if (e < rowptr2[BATCH]) flag[srcs2[e]] = 1;
}

__global__ void compact_kernel(const int* __restrict__ flag, const int* __restrict__ partial,
                               const int* __restrict__ chunksum, int* __restrict__ list,
                               int* __restrict__ countp, int n)
{
    int i = blockIdx.x * 256 + threadIdx.x;
    if (i >= n) return;
    int pos = partial[i] + chunksum[i >> 8];
    if (flag[i]) list[pos] = i;
    if (i == n - 1) countp[0] = pos + flag[i];
}

// ---------------- fused dual-edge-type gather ----------------
// For each dst d: softmax-weighted aggregation over edge type 1 (heads 0-3,
// H cols 0-511) and type 2 (heads 4-7, H cols 512-1023), then +b1+b2 and
// optional leaky-relu(0.01). H stride 1024, Out stride 512, both bf16.
__global__ void gather2_kernel(const int* __restrict__ rowptr1, const int* __restrict__ srcs1,
                               const int* __restrict__ rowptr2, const int* __restrict__ srcs2,
                               const float* __restrict__ asrc, const float* __restrict__ adst,
                               const unsigned short* __restrict__ H,
                               const float* __restrict__ b1, const float* __restrict__ b2,
                               unsigned short* __restrict__ Out, int ndst, int do_lrelu)
{
    int d = blockIdx.x * 4 + (threadIdx.x >> 6);
    if (d >= ndst) return;
    int lane = threadIdx.x & 63;
    int head = lane >> 4;      // 128 cols per head = 16 lanes * 8
    int col = lane * 8;
    float r[8], acc[8];
    // ---- edge type 1: heads 0-3, H cols [0,512) ----
    {
        int beg = rowptr1[d], end = rowptr1[d + 1];
        float ad = adst[(size_t)d * 8 + head];
        float den = 0.f;
#pragma unroll
        for (int k = 0; k < 8; k++) acc[k] = 0.f;
        for (int j = beg; j < end; j++) {
            int s = srcs1[j];
            float v = asrc[(size_t)s * 8 + head] + ad;
            v = v > 0.f ? v : 0.2f * v;
            float ex = expf(v);
            den += ex;
            short8 hv = *(const short8*)(H + (size_t)s * 1024 + col);
#pragma unroll
            for (int k = 0; k < 8; k++) acc[k] += ex * bf2f((unsigned short)hv[k]);
        }
        float inv = den > 0.f ? 1.f / den : 0.f;
#pragma unroll
        for (int k = 0; k < 8; k++) r[k] = acc[k] * inv;
    }
    // ---- edge type 2: heads 4-7, H cols [512,1024) ----
    {
        int beg = rowptr2[d], end = rowptr2[d + 1];
        float ad = adst[(size_t)d * 8 + 4 + head];
        float den = 0.f;
#pragma unroll
        for (int k = 0; k < 8; k++) acc[k] = 0.f;
        for (int j = beg; j < end; j++) {
            int s = srcs2[j];
            float v = asrc[(size_t)s * 8 + 4 + head] + ad;
            v = v > 0.f ? v : 0.2f * v;
            float ex = expf(v);
            den += ex;
            short8 hv = *(const short8*)(H + (size_t)s * 1024 + 512 + col);
#pragma unroll
            for (int k = 0; k < 8; k++) acc[k] += ex * bf2f((unsigned short)hv[k]);
        }
        float inv = den > 0.f ? 1.f / den : 0.f;
#pragma unroll
        for (int k = 0; k < 8; k++) r[k] += acc[k] * inv;
    }
    short8 o;
#pragma unroll
    for (int k = 0; k < 8; k++) {
        float f = r[k] + b1[col + k] + b2[col + k];
        if (do_lrelu) f = f > 0.f ? f : 0.01f * f;
        o[k] = (short)f2bf(f);
    }
    *(short8*)(Out + (size_t)d * 512 + col) = o;
}

// W[K][N] fp32 -> WT[N][K] bf16
__global__ void transpose_conv_kernel(const float* __restrict__ W, unsigned short* __restrict__ WT,
                                      int K, int N)
{
    int idx = blockIdx.x * blockDim.x + threadIdx.x;
    if (idx >= K * N) return;
    int n = idx / K, k = idx - n * K;
    WT[idx] = f2bf(W[(size_t)k * N + n]);
}

extern "C" void kernel_launch(void* const* d_in, const int* in_sizes, int n_in,
                              void* d_out, int out_size, void* d_ws, size_t ws_size,
                              hipStream_t stream)
{
    const float* x    = (const float*)d_in[0];
    const int* e1s    = (const int*)d_in[1];
    const int* e1d    = (const int*)d_in[2];
    const int* e2s    = (const int*)d_in[3];
    const int* e2d    = (const int*)d_in[4];
    const float* w0a  = (const float*)d_in[6];
    const float* as0a = (const float*)d_in[7];
    const float* ad0a = (const float*)d_in[8];
    const float* b0a  = (const float*)d_in[9];
    const float* w0b  = (const float*)d_in[10];
    const float* as0b = (const float*)d_in[11];
    const float* ad0b = (const float*)d_in[12];
    const float* b0b  = (const float*)d_in[13];
    const float* w1a  = (const float*)d_in[14];
    const float* as1a = (const float*)d_in[15];
    const float* ad1a = (const float*)d_in[16];
    const float* b1a  = (const float*)d_in[17];
    const float* w1b  = (const float*)d_in[18];
    const float* as1b = (const float*)d_in[19];
    const float* ad1b = (const float*)d_in[20];
    const float* b1b  = (const float*)d_in[21];
    const float* linw = (const float*)d_in[22];
    const float* linb = (const float*)d_in[23];
    float* out = (float*)d_out;
    (void)in_sizes; (void)n_in; (void)out_size;

    char* ws = (char*)d_ws;
    size_t off = 0;
    auto carve = [&](size_t bytes) -> void* {
        void* p = ws + off; off += (bytes + 255) & ~(size_t)255; return p;
    };
    unsigned short* WT0 = (unsigned short*)carve((size_t)2 * H_FEATS * IN_FEATS * 2); // [1024][1024]
    unsigned short* WT1 = (unsigned short*)carve((size_t)2 * H_FEATS * H_FEATS * 2);  // [1024][512]
    unsigned short* WTl = (unsigned short*)carve((size_t)N_CLASSES * H_FEATS * 2);
    unsigned short* Hbf = (unsigned short*)carve((size_t)N_NODES * 1024 * 2);  // fused conv out / l1 out
    unsigned short* H1  = (unsigned short*)carve((size_t)N_NODES * H_FEATS * 2);
    unsigned short* h2s = (unsigned short*)carve((size_t)BATCH * H_FEATS * 2);
    float* asrc = (float*)carve((size_t)N_NODES * 8 * 4);
    float* adst = (float*)carve((size_t)N_NODES * 8 * 4);
    int* rowptr1 = (int*)carve((size_t)(N_NODES + 1) * 4);
    int* rowptr2 = (int*)carve((size_t)(N_NODES + 1) * 4);
    int* srcs1   = (int*)carve((size_t)N_EDGES * 4);
    int* srcs2   = (int*)carve((size_t)N_EDGES * 4);
    int* cnt     = (int*)carve((size_t)N_NODES * 4);   // histogram / cursor / flag
    int* partial = (int*)carve((size_t)N_NODES * 4);
    int* chunksum= (int*)carve((size_t)512 * 4);
    int* list    = (int*)carve((size_t)N_NODES * 4);
    int* countp  = (int*)carve(256);
    // x-as-bf16 is large (205 MB): only use it if the workspace is big enough.
    // Decision depends only on ws_size -> identical on every call (capture-safe).
    unsigned short* xbf = nullptr;
    {
        size_t need = (size_t)N_NODES * IN_FEATS * 2;
        if (off + need <= ws_size) xbf = (unsigned short*)carve(need);
    }

    const int NCHUNK = (N_NODES + 255) / 256;   // 391
    const int MT = (N_NODES + 127) / 128;       // 782 m-tiles

    // --- weight transposes (a-half then b-half stacked along N) ---
    {
        int t0 = IN_FEATS * H_FEATS;
        transpose_conv_kernel<<<(t0 + 255) / 256, 256, 0, stream>>>(w0a, WT0, IN_FEATS, H_FEATS);
        transpose_conv_kernel<<<(t0 + 255) / 256, 256, 0, stream>>>(w0b, WT0 + (size_t)H_FEATS * IN_FEATS, IN_FEATS, H_FEATS);
        int t1 = H_FEATS * H_FEATS;
        transpose_conv_kernel<<<(t1 + 255) / 256, 256, 0, stream>>>(w1a, WT1, H_FEATS, H_FEATS);
        transpose_conv_kernel<<<(t1 + 255) / 256, 256, 0, stream>>>(w1b, WT1 + (size_t)H_FEATS * H_FEATS, H_FEATS, H_FEATS);
        int t2 = H_FEATS * N_CLASSES;
        transpose_conv_kernel<<<(t2 + 255) / 256, 256, 0, stream>>>(linw, WTl, H_FEATS, N_CLASSES);
    }

    // --- x -> bf16 (if workspace allows) ---
    if (xbf) {
        int n8 = N_NODES * IN_FEATS / 8;
        cvt_bf16_kernel<<<(n8 + 255) / 256, 256, 0, stream>>>(x, xbf, n8);
    }

    // --- CSR build for both edge types ---
    auto build_csr = [&](const int* src, const int* dst, int* rowptr, int* srcs_sorted) {
        hipMemsetAsync(cnt, 0, (size_t)N_NODES * 4, stream);
        hist_kernel<<<(N_EDGES + 255) / 256, 256, 0, stream>>>(dst, cnt, N_EDGES);
        scan1_kernel<<<NCHUNK, 256, 0, stream>>>(cnt, partial, chunksum, N_NODES);
        scan2_kernel<<<1, 512, 0, stream>>>(chunksum, NCHUNK);
        scan3_kernel<<<NCHUNK, 256, 0, stream>>>(partial, chunksum, rowptr, cnt, N_NODES, N_EDGES);
        fill_kernel<<<(N_EDGES + 255) / 256, 256, 0, stream>>>(src, dst, cnt, srcs_sorted, N_EDGES);
    };
    build_csr(e1s, e1d, rowptr1, srcs1);
    build_csr(e2s, e2d, rowptr2, srcs2);

    const void* xa = xbf ? (const void*)xbf : (const void*)x;
    int xa_fp32 = xbf ? 0 : 1;

    // --- layer 0: one fused N=1024 GEMM (both edge-type convs), then one gather ---
    hipMemsetAsync(asrc, 0, (size_t)N_NODES * 8 * 4, stream);
    hipMemsetAsync(adst, 0, (size_t)N_NODES * 8 * 4, stream);
    gemm_kernel<<<MT * 8, 256, 0, stream>>>(xa, xa_fp32, WT0, Hbf, nullptr,
                                            as0a, ad0a, as0b, ad0b, asrc, adst,
                                            nullptr, nullptr,
                                            N_NODES, 1024, 8, IN_FEATS, 1);
    gather2_kernel<<<(N_NODES + 3) / 4, 256, 0, stream>>>(rowptr1, srcs1, rowptr2, srcs2,
                                                          asrc, adst, Hbf, b0a, b0b,
                                                          H1, N_NODES, 1);

    // --- mark + compact the node set actually needed by layer 1 ---
    hipMemsetAsync(cnt, 0, (size_t)N_NODES * 4, stream);
    mark_kernel<<<(N_EDGES + 255) / 256, 256, 0, stream>>>(rowptr1, srcs1, rowptr2, srcs2, cnt, N_EDGES);
    scan1_kernel<<<NCHUNK, 256, 0, stream>>>(cnt, partial, chunksum, N_NODES);
    scan2_kernel<<<1, 512, 0, stream>>>(chunksum, NCHUNK);
    compact_kernel<<<NCHUNK, 256, 0, stream>>>(cnt, partial, chunksum, list, countp, N_NODES);

    // --- layer 1: compacted fused GEMM (scatter rows into Hbf), then gather over BATCH ---
    hipMemsetAsync(asrc, 0, (size_t)N_NODES * 8 * 4, stream);
    hipMemsetAsync(adst, 0, (size_t)N_NODES * 8 * 4, stream);
    gemm_kernel<<<MT * 8, 256, 0, stream>>>(H1, 0, WT1, Hbf, nullptr,
                                            as1a, ad1a, as1b, ad1b, asrc, adst,
                                            list, countp,
                                            N_NODES, 1024, 8, H_FEATS, 1);
    gather2_kernel<<<(BATCH + 3) / 4, 256, 0, stream>>>(rowptr1, srcs1, rowptr2, srcs2,
                                                        asrc, adst, Hbf, b1a, b1b,
                                                        h2s, BATCH, 0);

    // --- classification head ---
    const int HN_T = (N_CLASSES + 127) / 128;   // 24
    gemm_kernel<<<(BATCH / 128) * HN_T, 256, 0, stream>>>(h2s, 0, WTl, out, linb,
                                                          nullptr, nullptr, nullptr, nullptr,
                                                          nullptr, nullptr, nullptr, nullptr,
                                                          BATCH, N_CLASSES, HN_T, H_FEATS, 0);
}

// Round 2
// 850.890 us; speedup vs baseline: 1.8966x; 1.6394x over previous
//
#include <hip/hip_runtime.h>

#define N_NODES 100000
#define N_EDGES 200000
#define IN_FEATS 1024
#define H_FEATS 512
#define N_HEADS 4
#define HEAD_DIM 128
#define N_CLASSES 2983
#define BATCH 1024

typedef __attribute__((ext_vector_type(8))) short short8;
typedef __attribute__((ext_vector_type(4))) float floatx4;

typedef __attribute__((address_space(1))) void global_as_void;
typedef __attribute__((address_space(3))) void lds_as_void;

__device__ __forceinline__ float bf2f(unsigned short u) {
    union { unsigned int i; float f; } x; x.i = ((unsigned int)u) << 16; return x.f;
}
__device__ __forceinline__ unsigned short f2bf(float f) {
    union { float f; unsigned int i; } x; x.f = f;
    unsigned int r = x.i + 0x7FFFu + ((x.i >> 16) & 1u);
    return (unsigned short)(r >> 16);
}
__device__ __forceinline__ void load_lds16(const void* g, void* l) {
    __builtin_amdgcn_global_load_lds((const global_as_void*)g, (lds_as_void*)l, 16, 0, 0);
}

// ---------------- GEMM ----------------
// C[M,N] = A @ BT^T.  A: bf16 (a_fp32=0) or fp32 (a_fp32=1).
// Row indirection: countp = device row count (null -> M); rowlist maps
// compact row -> node id.  a_dense=1: A is stored compact (read dense index),
// C stores + att atomics scatter via rowlist.  a_dense=0: A also via rowlist.
// XCD swizzle (n_tiles==8 only): xcd = bid&7 owns m-tiles {xcd + 8*t}, walking
// all 8 n-tiles of one m-tile consecutively -> A-tile L2-resident per XCD.
// Grid for n_tiles==8 must be 784*8 (mt in [0,784) bijective).
// att epilogue: head h = nt (0..7); h<4 -> att_s/att_d, h>=4 -> att_s2/att_d2,
// logits atomicAdd at node*8 + h.
// LDS swizzle: 16B slot c of row r holds global k-chunk c ^ ((r>>1)&3).
__global__ __launch_bounds__(256, 3)
void gemm_kernel(const void* __restrict__ Ain, int a_fp32, int a_dense,
                 const unsigned short* __restrict__ BT,
                 void* __restrict__ Cout, const float* __restrict__ bias,
                 const float* __restrict__ att_s, const float* __restrict__ att_d,
                 const float* __restrict__ att_s2, const float* __restrict__ att_d2,
                 float* __restrict__ asrc, float* __restrict__ adst,
                 const int* __restrict__ rowlist, const int* __restrict__ countp,
                 int M, int N, int n_tiles, int K, int out_bf16)
{
    __shared__ __attribute__((aligned(16))) unsigned short As[128 * 32];
    __shared__ __attribute__((aligned(16))) unsigned short Bs[128 * 32];
    const int tid  = threadIdx.x;
    const int lane = tid & 63;
    const int wave = tid >> 6;
    const int bid = blockIdx.x;
    int mt, nt;
    if (n_tiles == 8) {
        int k8 = bid & 7, j = bid >> 3;
        nt = j & 7;
        mt = k8 + ((j >> 3) << 3);
    } else {
        mt = bid / n_tiles;
        nt = bid - mt * n_tiles;
    }
    const int m0 = mt * 128;
    const int n0 = nt * 128;
    int Mv = M;
    if (countp) Mv = countp[0];
    if (m0 >= Mv) return;           // uniform across block: safe before barriers
    const int wr = (wave >> 1) * 64;
    const int wc = (wave & 1) * 64;
    const int lm = lane & 15;
    const int quad = lane >> 4;

    auto arow = [&](int r) -> int {
        int gr = m0 + r; if (gr > Mv - 1) gr = Mv - 1;
        if (rowlist && !a_dense) gr = rowlist[gr];
        return gr;
    };

    floatx4 acc[4][4];
#pragma unroll
    for (int i = 0; i < 4; i++)
#pragma unroll
        for (int j = 0; j < 4; j++) acc[i][j] = (floatx4)0.0f;

    for (int k0 = 0; k0 < K; k0 += 32) {
        __syncthreads();
        if (a_fp32) {
            // VALU staging: fp32 -> bf16, same swizzled layout
            int row = tid >> 2;
            int slot = tid & 3;
#pragma unroll
            for (int p = 0; p < 2; p++) {
                int r = p * 64 + row;
                int gr = arow(r);
                int gc = (slot ^ ((r >> 1) & 3)) * 8;
                const float* ap = (const float*)Ain + (size_t)gr * K + k0 + gc;
                floatx4 f0 = *(const floatx4*)ap;
                floatx4 f1 = *(const floatx4*)(ap + 4);
                short8 v;
                v[0] = (short)f2bf(f0[0]); v[1] = (short)f2bf(f0[1]);
                v[2] = (short)f2bf(f0[2]); v[3] = (short)f2bf(f0[3]);
                v[4] = (short)f2bf(f1[0]); v[5] = (short)f2bf(f1[1]);
                v[6] = (short)f2bf(f1[2]); v[7] = (short)f2bf(f1[3]);
                *(short8*)&As[r * 32 + slot * 8] = v;
            }
        } else {
            // direct global->LDS DMA, 16B/lane; dest = wave-uniform base + lane*16
#pragma unroll
            for (int i = 0; i < 2; i++) {
                int r = wave * 32 + i * 16 + (lane >> 2);
                int gr = arow(r);
                int gc = ((lane & 3) ^ ((r >> 1) & 3)) * 8;
                load_lds16((const unsigned short*)Ain + (size_t)gr * K + k0 + gc,
                           (char*)As + (size_t)(wave * 2 + i) * 1024);
            }
        }
#pragma unroll
        for (int i = 0; i < 2; i++) {
            int r = wave * 32 + i * 16 + (lane >> 2);
            int gn = n0 + r; if (gn > N - 1) gn = N - 1;
            int gc = ((lane & 3) ^ ((r >> 1) & 3)) * 8;
            load_lds16(BT + (size_t)gn * K + k0 + gc,
                       (char*)Bs + (size_t)(wave * 2 + i) * 1024);
        }
        __syncthreads();
        short8 af[4], bfr[4];
#pragma unroll
        for (int i = 0; i < 4; i++) {
            int ra = wr + i * 16 + lm;
            af[i] = *(const short8*)&As[ra * 32 + ((quad ^ ((ra >> 1) & 3)) << 3)];
            int rb = wc + i * 16 + lm;
            bfr[i] = *(const short8*)&Bs[rb * 32 + ((quad ^ ((rb >> 1) & 3)) << 3)];
        }
#pragma unroll
        for (int i = 0; i < 4; i++)
#pragma unroll
            for (int j = 0; j < 4; j++)
                acc[i][j] = __builtin_amdgcn_mfma_f32_16x16x32_bf16(af[i], bfr[j], acc[i][j], 0, 0, 0);
    }

    // fused attention logits (this block covers exactly one head's 128 cols)
    if (att_s) {
        const int h = nt;
        const float* wsp = (h < 4) ? att_s : att_s2;
        const float* wdp = (h < 4) ? att_d : att_d2;
        const int hh = h & 3;
#pragma unroll
        for (int i = 0; i < 4; i++) {
#pragma unroll
            for (int r = 0; r < 4; r++) {
                float ss = 0.f, sd = 0.f;
#pragma unroll
                for (int j = 0; j < 4; j++) {
                    int c = wc + j * 16 + lm;
                    ss += acc[i][j][r] * wsp[hh * HEAD_DIM + c];
                    sd += acc[i][j][r] * wdp[hh * HEAD_DIM + c];
                }
#pragma unroll
                for (int off = 1; off < 16; off <<= 1) {
                    ss += __shfl_xor(ss, off);
                    sd += __shfl_xor(sd, off);
                }
                int grl = m0 + wr + i * 16 + quad * 4 + r;
                if (lm == 0 && grl < Mv) {
                    int gr = rowlist ? rowlist[grl] : grl;
                    atomicAdd(&asrc[(size_t)gr * 8 + h], ss);
                    atomicAdd(&adst[(size_t)gr * 8 + h], sd);
                }
            }
        }
    }

    // C store: C/D layout col=lane&15, row=quad*4+reg
#pragma unroll
    for (int i = 0; i < 4; i++) {
        int grb = wr + i * 16 + quad * 4;
#pragma unroll
        for (int j = 0; j < 4; j++) {
            int gc = n0 + wc + j * 16 + lm;
            if (gc < N) {
#pragma unroll
                for (int r = 0; r < 4; r++) {
                    int grl = m0 + grb + r;
                    if (grl < Mv) {
                        int gr = rowlist ? rowlist[grl] : grl;
                        float v = acc[i][j][r];
                        if (out_bf16) {
                            ((unsigned short*)Cout)[(size_t)gr * N + gc] = f2bf(v);
                        } else {
                            float b = bias ? bias[gc] : 0.0f;
                            ((float*)Cout)[(size_t)gr * N + gc] = v + b;
                        }
                    }
                }
            }
        }
    }
}

// ---------------- compact-row fp32 -> bf16 convert ----------------
// Y[i][:] = bf16(X[list[i]][:]) for i < countp[0]; row width IN_FEATS.
__global__ void cvt_rows_kernel(const float* __restrict__ X, const int* __restrict__ list,
                                const int* __restrict__ countp, unsigned short* __restrict__ Y)
{
    int i = blockIdx.x * 2 + (threadIdx.x >> 7);
    if (i >= countp[0]) return;
    int col = (threadIdx.x & 127) * 8;
    const floatx4* xp = (const floatx4*)(X + (size_t)list[i] * IN_FEATS + col);
    floatx4 f0 = xp[0], f1 = xp[1];
    short8 v;
    v[0] = (short)f2bf(f0[0]); v[1] = (short)f2bf(f0[1]);
    v[2] = (short)f2bf(f0[2]); v[3] = (short)f2bf(f0[3]);
    v[4] = (short)f2bf(f1[0]); v[5] = (short)f2bf(f1[1]);
    v[6] = (short)f2bf(f1[2]); v[7] = (short)f2bf(f1[3]);
    *(short8*)(Y + (size_t)i * IN_FEATS + col) = v;
}

// ---------------- CSR build ----------------
__global__ void hist_kernel(const int* __restrict__ dst, int* __restrict__ cnt, int E)
{
    int e = blockIdx.x * blockDim.x + threadIdx.x;
    if (e < E) atomicAdd(&cnt[dst[e]], 1);
}

__global__ void scan1_kernel(const int* __restrict__ cnt, int* __restrict__ partial,
                             int* __restrict__ chunksum, int n)
{
    __shared__ int sm[256];
    int t = threadIdx.x;
    int i = blockIdx.x * 256 + t;
    int v = (i < n) ? cnt[i] : 0;
    sm[t] = v; __syncthreads();
    int val = v;
#pragma unroll
    for (int off = 1; off < 256; off <<= 1) {
        int u = (t >= off) ? sm[t - off] : 0;
        __syncthreads();
        val += u; sm[t] = val;
        __syncthreads();
    }
    if (i < n) partial[i] = val - v;
    if (t == 255) chunksum[blockIdx.x] = val;
}

__global__ void scan2_kernel(int* __restrict__ chunksum, int n)
{
    __shared__ int sm[512];
    int t = threadIdx.x;
    int v = (t < n) ? chunksum[t] : 0;
    sm[t] = v; __syncthreads();
    int val = v;
#pragma unroll
    for (int off = 1; off < 512; off <<= 1) {
        int u = (t >= off) ? sm[t - off] : 0;
        __syncthreads();
        val += u; sm[t] = val;
        __syncthreads();
    }
    if (t < n) chunksum[t] = val - v;
}

__global__ void scan3_kernel(const int* __restrict__ partial, const int* __restrict__ chunksum,
                             int* __restrict__ rowptr, int* __restrict__ cursor, int n, int E)
{
    int i = blockIdx.x * 256 + threadIdx.x;
    if (i < n) {
        int r = partial[i] + chunksum[i >> 8];
        rowptr[i] = r;
        cursor[i] = r;
    }
    if (i == 0) rowptr[n] = E;
}

__global__ void fill_kernel(const int* __restrict__ src, const int* __restrict__ dst,
                            int* __restrict__ cursor, int* __restrict__ srcs_sorted, int E)
{
    int e = blockIdx.x * blockDim.x + threadIdx.x;
    if (e < E) {
        int p = atomicAdd(&cursor[dst[e]], 1);
        srcs_sorted[p] = src[e];
    }
}

// ---------------- frontier marking / compaction ----------------
// F1: nodes needed as layer-1 GEMM rows = srcs of edges with dst < BATCH
// (both types, via CSR prefix) plus the BATCH seed nodes.
__global__ void mark1_kernel(const int* __restrict__ rowptr1, const int* __restrict__ srcs1,
                             const int* __restrict__ rowptr2, const int* __restrict__ srcs2,
                             int* __restrict__ flag, int E)
{
    int e = blockIdx.x * blockDim.x + threadIdx.x;
    if (e >= E) return;
    if (e < BATCH) flag[e] = 1;
    if (e < rowptr1[BATCH]) flag[srcs1[e]] = 1;
    if (e < rowptr2[BATCH]) flag[srcs2[e]] = 1;
}

// F0: nodes needed as layer-0 GEMM rows = srcs of edges whose dst is in F1
// (both types), plus F1 itself (its adst logits come from the same GEMM).
__global__ void mark0_kernel(const int* __restrict__ e1s, const int* __restrict__ e1d,
                             const int* __restrict__ e2s, const int* __restrict__ e2d,
                             const int* __restrict__ flag1, int* __restrict__ flag0,
                             int E, int Nn)
{
    int i = blockIdx.x * blockDim.x + threadIdx.x;
    if (i < E) {
        if (flag1[e1d[i]]) flag0[e1s[i]] = 1;
        if (flag1[e2d[i]]) flag0[e2s[i]] = 1;
    }
    if (i < Nn && flag1[i]) flag0[i] = 1;
}

__global__ void compact_kernel(const int* __restrict__ flag, const int* __restrict__ partial,
                               const int* __restrict__ chunksum, int* __restrict__ list,
                               int* __restrict__ countp, int n)
{
    int i = blockIdx.x * 256 + threadIdx.x;
    if (i >= n) return;
    int pos = partial[i] + chunksum[i >> 8];
    if (flag[i]) list[pos] = i;
    if (i == n - 1) countp[0] = pos + flag[i];
}

// ---------------- fused dual-edge-type gather ----------------
// For dst-slot i (node d = dlist ? dlist[i] : i, i < (dcountp ? *dcountp : ndst)):
// softmax aggregation over type 1 (heads 0-3, H cols 0-511) and type 2
// (heads 4-7, H cols 512-1023), +b1+b2, optional lrelu(0.01).
// H stride 1024 (node-indexed), Out stride 512 (slot-indexed, dense).
__global__ void gather2_kernel(const int* __restrict__ rowptr1, const int* __restrict__ srcs1,
                               const int* __restrict__ rowptr2, const int* __restrict__ srcs2,
                               const float* __restrict__ asrc, const float* __restrict__ adst,
                               const unsigned short* __restrict__ H,
                               const float* __restrict__ b1, const float* __restrict__ b2,
                               const int* __restrict__ dlist, const int* __restrict__ dcountp,
                               unsigned short* __restrict__ Out, int ndst, int do_lrelu)
{
    int i = blockIdx.x * 4 + (threadIdx.x >> 6);
    int nd = dcountp ? dcountp[0] : ndst;
    if (i >= nd) return;
    int d = dlist ? dlist[i] : i;
    int lane = threadIdx.x & 63;
    int head = lane >> 4;      // 128 cols per head = 16 lanes * 8
    int col = lane * 8;
    float r[8], acc[8];
    // ---- edge type 1: heads 0-3, H cols [0,512) ----
    {
        int beg = rowptr1[d], end = rowptr1[d + 1];
        float ad = adst[(size_t)d * 8 + head];
        float den = 0.f;
#pragma unroll
        for (int k = 0; k < 8; k++) acc[k] = 0.f;
        for (int j = beg; j < end; j++) {
            int s = srcs1[j];
            float v = asrc[(size_t)s * 8 + head] + ad;
            v = v > 0.f ? v : 0.2f * v;
            float ex = expf(v);
            den += ex;
            short8 hv = *(const short8*)(H + (size_t)s * 1024 + col);
#pragma unroll
            for (int k = 0; k < 8; k++) acc[k] += ex * bf2f((unsigned short)hv[k]);
        }
        float inv = den > 0.f ? 1.f / den : 0.f;
#pragma unroll
        for (int k = 0; k < 8; k++) r[k] = acc[k] * inv;
    }
    // ---- edge type 2: heads 4-7, H cols [512,1024) ----
    {
        int beg = rowptr2[d], end = rowptr2[d + 1];
        float ad = adst[(size_t)d * 8 + 4 + head];
        float den = 0.f;
#pragma unroll
        for (int k = 0; k < 8; k++) acc[k] = 0.f;
        for (int j = beg; j < end; j++) {
            int s = srcs2[j];
            float v = asrc[(size_t)s * 8 + 4 + head] + ad;
            v = v > 0.f ? v : 0.2f * v;
            float ex = expf(v);
            den += ex;
            short8 hv = *(const short8*)(H + (size_t)s * 1024 + 512 + col);
#pragma unroll
            for (int k = 0; k < 8; k++) acc[k] += ex * bf2f((unsigned short)hv[k]);
        }
        float inv = den > 0.f ? 1.f / den : 0.f;
#pragma unroll
        for (int k = 0; k < 8; k++) r[k] += acc[k] * inv;
    }
    short8 o;
#pragma unroll
    for (int k = 0; k < 8; k++) {
        float f = r[k] + b1[col + k] + b2[col + k];
        if (do_lrelu) f = f > 0.f ? f : 0.01f * f;
        o[k] = (short)f2bf(f);
    }
    *(short8*)(Out + (size_t)i * 512 + col) = o;
}

// W[K][N] fp32 -> WT[N][K] bf16
__global__ void transpose_conv_kernel(const float* __restrict__ W, unsigned short* __restrict__ WT,
                                      int K, int N)
{
    int idx = blockIdx.x * blockDim.x + threadIdx.x;
    if (idx >= K * N) return;
    int n = idx / K, k = idx - n * K;
    WT[idx] = f2bf(W[(size_t)k * N + n]);
}

extern "C" void kernel_launch(void* const* d_in, const int* in_sizes, int n_in,
                              void* d_out, int out_size, void* d_ws, size_t ws_size,
                              hipStream_t stream)
{
    const float* x    = (const float*)d_in[0];
    const int* e1s    = (const int*)d_in[1];
    const int* e1d    = (const int*)d_in[2];
    const int* e2s    = (const int*)d_in[3];
    const int* e2d    = (const int*)d_in[4];
    const float* w0a  = (const float*)d_in[6];
    const float* as0a = (const float*)d_in[7];
    const float* ad0a = (const float*)d_in[8];
    const float* b0a  = (const float*)d_in[9];
    const float* w0b  = (const float*)d_in[10];
    const float* as0b = (const float*)d_in[11];
    const float* ad0b = (const float*)d_in[12];
    const float* b0b  = (const float*)d_in[13];
    const float* w1a  = (const float*)d_in[14];
    const float* as1a = (const float*)d_in[15];
    const float* ad1a = (const float*)d_in[16];
    const float* b1a  = (const float*)d_in[17];
    const float* w1b  = (const float*)d_in[18];
    const float* as1b = (const float*)d_in[19];
    const float* ad1b = (const float*)d_in[20];
    const float* b1b  = (const float*)d_in[21];
    const float* linw = (const float*)d_in[22];
    const float* linb = (const float*)d_in[23];
    float* out = (float*)d_out;
    (void)in_sizes; (void)n_in; (void)out_size;

    char* ws = (char*)d_ws;
    size_t off = 0;
    auto carve = [&](size_t bytes) -> void* {
        void* p = ws + off; off += (bytes + 255) & ~(size_t)255; return p;
    };
    unsigned short* WT0 = (unsigned short*)carve((size_t)2 * H_FEATS * IN_FEATS * 2); // [1024][1024]
    unsigned short* WT1 = (unsigned short*)carve((size_t)2 * H_FEATS * H_FEATS * 2);  // [1024][512]
    unsigned short* WTl = (unsigned short*)carve((size_t)N_CLASSES * H_FEATS * 2);
    unsigned short* Hbf = (unsigned short*)carve((size_t)N_NODES * 1024 * 2);  // GEMM out, node-indexed
    unsigned short* H1c = (unsigned short*)carve((size_t)N_NODES * H_FEATS * 2); // layer-0 gather out, F1-compact
    unsigned short* h2s = (unsigned short*)carve((size_t)BATCH * H_FEATS * 2);
    float* asrc = (float*)carve((size_t)N_NODES * 8 * 4);
    float* adst = (float*)carve((size_t)N_NODES * 8 * 4);
    int* rowptr1 = (int*)carve((size_t)(N_NODES + 1) * 4);
    int* rowptr2 = (int*)carve((size_t)(N_NODES + 1) * 4);
    int* srcs1   = (int*)carve((size_t)N_EDGES * 4);
    int* srcs2   = (int*)carve((size_t)N_EDGES * 4);
    int* cnt     = (int*)carve((size_t)N_NODES * 4);   // histogram / cursor
    int* partial = (int*)carve((size_t)N_NODES * 4);
    int* chunksum= (int*)carve((size_t)512 * 4);
    int* flag1   = (int*)carve((size_t)N_NODES * 4);
    int* flag0   = (int*)carve((size_t)N_NODES * 4);
    int* list1   = (int*)carve((size_t)N_NODES * 4);
    int* list0   = (int*)carve((size_t)N_NODES * 4);
    int* count1  = (int*)carve(256);
    int* count0  = (int*)carve(256);
    // compact bf16 A for layer 0 (worst case all nodes): only if ws allows.
    // Decision depends only on ws_size -> identical every call (capture-safe).
    unsigned short* xc = nullptr;
    {
        size_t need = (size_t)N_NODES * IN_FEATS * 2;
        if (off + need <= ws_size) xc = (unsigned short*)carve(need);
    }

    const int NCHUNK = (N_NODES + 255) / 256;   // 391
    const int MT8 = (((N_NODES + 127) / 128) + 7) & ~7;   // 784, multiple of 8 for swizzle

    // --- weight transposes (a-half then b-half stacked along N) ---
    {
        int t0 = IN_FEATS * H_FEATS;
        transpose_conv_kernel<<<(t0 + 255) / 256, 256, 0, stream>>>(w0a, WT0, IN_FEATS, H_FEATS);
        transpose_conv_kernel<<<(t0 + 255) / 256, 256, 0, stream>>>(w0b, WT0 + (size_t)H_FEATS * IN_FEATS, IN_FEATS, H_FEATS);
        int t1 = H_FEATS * H_FEATS;
        transpose_conv_kernel<<<(t1 + 255) / 256, 256, 0, stream>>>(w1a, WT1, H_FEATS, H_FEATS);
        transpose_conv_kernel<<<(t1 + 255) / 256, 256, 0, stream>>>(w1b, WT1 + (size_t)H_FEATS * H_FEATS, H_FEATS, H_FEATS);
        int t2 = H_FEATS * N_CLASSES;
        transpose_conv_kernel<<<(t2 + 255) / 256, 256, 0, stream>>>(linw, WTl, H_FEATS, N_CLASSES);
    }

    // --- CSR build for both edge types ---
    auto build_csr = [&](const int* src, const int* dst, int* rowptr, int* srcs_sorted) {
        hipMemsetAsync(cnt, 0, (size_t)N_NODES * 4, stream);
        hist_kernel<<<(N_EDGES + 255) / 256, 256, 0, stream>>>(dst, cnt, N_EDGES);
        scan1_kernel<<<NCHUNK, 256, 0, stream>>>(cnt, partial, chunksum, N_NODES);
        scan2_kernel<<<1, 512, 0, stream>>>(chunksum, NCHUNK);
        scan3_kernel<<<NCHUNK, 256, 0, stream>>>(partial, chunksum, rowptr, cnt, N_NODES, N_EDGES);
        fill_kernel<<<(N_EDGES + 255) / 256, 256, 0, stream>>>(src, dst, cnt, srcs_sorted, N_EDGES);
    };
    build_csr(e1s, e1d, rowptr1, srcs1);
    build_csr(e2s, e2d, rowptr2, srcs2);

    // --- frontier F1 (layer-1 rows) and F0 (layer-0 rows) ---
    hipMemsetAsync(flag1, 0, (size_t)N_NODES * 4, stream);
    mark1_kernel<<<(N_EDGES + 255) / 256, 256, 0, stream>>>(rowptr1, srcs1, rowptr2, srcs2, flag1, N_EDGES);
    scan1_kernel<<<NCHUNK, 256, 0, stream>>>(flag1, partial, chunksum, N_NODES);
    scan2_kernel<<<1, 512, 0, stream>>>(chunksum, NCHUNK);
    compact_kernel<<<NCHUNK, 256, 0, stream>>>(flag1, partial, chunksum, list1, count1, N_NODES);

    hipMemsetAsync(flag0, 0, (size_t)N_NODES * 4, stream);
    mark0_kernel<<<(N_EDGES + 255) / 256, 256, 0, stream>>>(e1s, e1d, e2s, e2d, flag1, flag0, N_EDGES, N_NODES);
    scan1_kernel<<<NCHUNK, 256, 0, stream>>>(flag0, partial, chunksum, N_NODES);
    scan2_kernel<<<1, 512, 0, stream>>>(chunksum, NCHUNK);
    compact_kernel<<<NCHUNK, 256, 0, stream>>>(flag0, partial, chunksum, list0, count0, N_NODES);

    // --- compact x rows -> bf16 (F0 only) ---
    if (xc) {
        cvt_rows_kernel<<<(N_NODES + 1) / 2, 256, 0, stream>>>(x, list0, count0, xc);
    }

    // --- layer 0: fused N=1024 GEMM over F0 rows, gather over F1 dsts ---
    hipMemsetAsync(asrc, 0, (size_t)N_NODES * 8 * 4, stream);
    hipMemsetAsync(adst, 0, (size_t)N_NODES * 8 * 4, stream);
    if (xc) {
        gemm_kernel<<<MT8 * 8, 256, 0, stream>>>(xc, 0, 1, WT0, Hbf, nullptr,
                                                 as0a, ad0a, as0b, ad0b, asrc, adst,
                                                 list0, count0,
                                                 N_NODES, 1024, 8, IN_FEATS, 1);
    } else {
        gemm_kernel<<<MT8 * 8, 256, 0, stream>>>(x, 1, 0, WT0, Hbf, nullptr,
                                                 as0a, ad0a, as0b, ad0b, asrc, adst,
                                                 list0, count0,
                                                 N_NODES, 1024, 8, IN_FEATS, 1);
    }
    gather2_kernel<<<(N_NODES + 3) / 4, 256, 0, stream>>>(rowptr1, srcs1, rowptr2, srcs2,
                                                          asrc, adst, Hbf, b0a, b0b,
                                                          list1, count1,
                                                          H1c, N_NODES, 1);

    // --- layer 1: compact GEMM over F1 rows (scatter into Hbf), gather over BATCH ---
    hipMemsetAsync(asrc, 0, (size_t)N_NODES * 8 * 4, stream);
    hipMemsetAsync(adst, 0, (size_t)N_NODES * 8 * 4, stream);
    gemm_kernel<<<MT8 * 8, 256, 0, stream>>>(H1c, 0, 1, WT1, Hbf, nullptr,
                                             as1a, ad1a, as1b, ad1b, asrc, adst,
                                             list1, count1,
                                             N_NODES, 1024, 8, H_FEATS, 1);
    gather2_kernel<<<(BATCH + 3) / 4, 256, 0, stream>>>(rowptr1, srcs1, rowptr2, srcs2,
                                                        asrc, adst, Hbf, b1a, b1b,
                                                        nullptr, nullptr,
                                                        h2s, BATCH, 0);

    // --- classification head ---
    const int HN_T = (N_CLASSES + 127) / 128;   // 24
    gemm_kernel<<<(BATCH / 128) * HN_T, 256, 0, stream>>>(h2s, 0, 0, WTl, out, linb,
                                                          nullptr, nullptr, nullptr, nullptr,
                                                          nullptr, nullptr, nullptr, nullptr,
                                                          BATCH, N_CLASSES, HN_T, H_FEATS, 0);
}

// Round 4
// 775.755 us; speedup vs baseline: 2.0803x; 1.0969x over previous
//
#include <hip/hip_runtime.h>

#define N_NODES 100000
#define N_EDGES 200000
#define IN_FEATS 1024
#define H_FEATS 512
#define N_HEADS 4
#define HEAD_DIM 128
#define N_CLASSES 2983
#define BATCH 1024

typedef __attribute__((ext_vector_type(8))) short short8;
typedef __attribute__((ext_vector_type(4))) float floatx4;

typedef __attribute__((address_space(1))) void global_as_void;
typedef __attribute__((address_space(3))) void lds_as_void;

__device__ __forceinline__ float bf2f(unsigned short u) {
    union { unsigned int i; float f; } x; x.i = ((unsigned int)u) << 16; return x.f;
}
__device__ __forceinline__ unsigned short f2bf(float f) {
    union { float f; unsigned int i; } x; x.f = f;
    unsigned int r = x.i + 0x7FFFu + ((x.i >> 16) & 1u);
    return (unsigned short)(r >> 16);
}
__device__ __forceinline__ void load_lds16(const void* g, void* l) {
    __builtin_amdgcn_global_load_lds((const global_as_void*)g, (lds_as_void*)l, 16, 0, 0);
}

// ---------------- GEMM ----------------
// C[M,N] = A @ BT^T.  A: bf16 (a_fp32=0) or fp32 (a_fp32=1).
// Row indirection: countp = device row count (null -> M); rowlist maps
// compact row -> node id.  a_dense=1: A stored compact (dense index);
// C stores + att logit stores scatter via rowlist.  a_dense=0: A via rowlist.
// All staging addresses hoisted out of the K-loop (rowlist read once).
// XCD swizzle (n_tiles==8): mt = (bid&7) + 8*(bid>>6), nt = (bid>>3)&7 ->
// one XCD walks all 8 n-tiles of its m-tile (A-tile L2-resident).
// att epilogue: head h = nt; h<4 -> att_s/att_d, h>=4 -> att_s2/att_d2.
// Row logits: each wave covers HALF the head cols (wc=0 -> 0-63, wc=64 ->
// 64-127), so the two wave-halves are summed in LDS (attbuf) before ONE
// plain store per (node,h).  (Round-3 bug: plain stores raced the halves.)
// LDS swizzle: 16B slot c of row r holds global k-chunk c ^ ((r>>1)&3).
__global__ __launch_bounds__(256, 3)
void gemm_kernel(const void* __restrict__ Ain, int a_fp32, int a_dense,
                 const unsigned short* __restrict__ BT,
                 void* __restrict__ Cout, const float* __restrict__ bias,
                 const float* __restrict__ att_s, const float* __restrict__ att_d,
                 const float* __restrict__ att_s2, const float* __restrict__ att_d2,
                 float* __restrict__ asrc, float* __restrict__ adst,
                 const int* __restrict__ rowlist, const int* __restrict__ countp,
                 int M, int N, int n_tiles, int K, int out_bf16)
{
    __shared__ __attribute__((aligned(16))) unsigned short As[128 * 32];
    __shared__ __attribute__((aligned(16))) unsigned short Bs[128 * 32];
    __shared__ float attbuf[128][4];   // [row][{ss,sd} x {half0,half1}]
    const int tid  = threadIdx.x;
    const int lane = tid & 63;
    const int wave = tid >> 6;
    const int bid = blockIdx.x;
    int mt, nt;
    if (n_tiles == 8) {
        mt = (bid & 7) + ((bid >> 6) << 3);
        nt = (bid >> 3) & 7;
    } else {
        mt = bid / n_tiles;
        nt = bid - mt * n_tiles;
    }
    const int m0 = mt * 128;
    const int n0 = nt * 128;
    int Mv = M;
    if (countp) Mv = countp[0];
    if (m0 >= Mv) return;           // uniform across block: safe before barriers
    const int wr = (wave >> 1) * 64;
    const int wc = (wave & 1) * 64;
    const int lm = lane & 15;
    const int quad = lane >> 4;

    auto arow = [&](int r) -> int {
        int gr = m0 + r; if (gr > Mv - 1) gr = Mv - 1;
        if (rowlist && !a_dense) gr = rowlist[gr];
        return gr;
    };

    // ---- hoisted staging addresses (invariant over K) ----
    const float* a_fp[2];
    const unsigned short* a_bf[2];
    char* a_lds[2];
    const unsigned short* b_bf[2];
    char* b_lds[2];
    if (a_fp32) {
        int row = tid >> 2, slot = tid & 3;
#pragma unroll
        for (int p = 0; p < 2; p++) {
            int r = p * 64 + row;
            a_fp[p] = (const float*)Ain + (size_t)arow(r) * K + (slot ^ ((r >> 1) & 3)) * 8;
        }
    } else {
#pragma unroll
        for (int i = 0; i < 2; i++) {
            int r = wave * 32 + i * 16 + (lane >> 2);
            a_bf[i] = (const unsigned short*)Ain + (size_t)arow(r) * K
                    + ((lane & 3) ^ ((r >> 1) & 3)) * 8;
            a_lds[i] = (char*)As + (size_t)(wave * 2 + i) * 1024;
        }
    }
#pragma unroll
    for (int i = 0; i < 2; i++) {
        int r = wave * 32 + i * 16 + (lane >> 2);
        int gn = n0 + r; if (gn > N - 1) gn = N - 1;
        b_bf[i] = BT + (size_t)gn * K + ((lane & 3) ^ ((r >> 1) & 3)) * 8;
        b_lds[i] = (char*)Bs + (size_t)(wave * 2 + i) * 1024;
    }

    floatx4 acc[4][4];
#pragma unroll
    for (int i = 0; i < 4; i++)
#pragma unroll
        for (int j = 0; j < 4; j++) acc[i][j] = (floatx4)0.0f;

    for (int k0 = 0; k0 < K; k0 += 32) {
        __syncthreads();
        if (a_fp32) {
            int row = tid >> 2, slot = tid & 3;
#pragma unroll
            for (int p = 0; p < 2; p++) {
                int r = p * 64 + row;
                floatx4 f0 = *(const floatx4*)(a_fp[p] + k0);
                floatx4 f1 = *(const floatx4*)(a_fp[p] + k0 + 4);
                short8 v;
                v[0] = (short)f2bf(f0[0]); v[1] = (short)f2bf(f0[1]);
                v[2] = (short)f2bf(f0[2]); v[3] = (short)f2bf(f0[3]);
                v[4] = (short)f2bf(f1[0]); v[5] = (short)f2bf(f1[1]);
                v[6] = (short)f2bf(f1[2]); v[7] = (short)f2bf(f1[3]);
                *(short8*)&As[r * 32 + slot * 8] = v;
            }
        } else {
#pragma unroll
            for (int i = 0; i < 2; i++)
                load_lds16(a_bf[i] + k0, a_lds[i]);
        }
#pragma unroll
        for (int i = 0; i < 2; i++)
            load_lds16(b_bf[i] + k0, b_lds[i]);
        __syncthreads();
        short8 af[4], bfr[4];
#pragma unroll
        for (int i = 0; i < 4; i++) {
            int ra = wr + i * 16 + lm;
            af[i] = *(const short8*)&As[ra * 32 + ((quad ^ ((ra >> 1) & 3)) << 3)];
            int rb = wc + i * 16 + lm;
            bfr[i] = *(const short8*)&Bs[rb * 32 + ((quad ^ ((rb >> 1) & 3)) << 3)];
        }
#pragma unroll
        for (int i = 0; i < 4; i++)
#pragma unroll
            for (int j = 0; j < 4; j++)
                acc[i][j] = __builtin_amdgcn_mfma_f32_16x16x32_bf16(af[i], bfr[j], acc[i][j], 0, 0, 0);
    }

    // fused attention logits (this block covers exactly one head's 128 cols;
    // each wave holds half the cols -> combine the two halves via LDS).
    if (att_s) {
        const int h = nt;
        const float* wsp = (h < 4) ? att_s : att_s2;
        const float* wdp = (h < 4) ? att_d : att_d2;
        const int hh = h & 3;
        const int half2 = (wc >> 6) * 2;   // 0 or 2
#pragma unroll
        for (int i = 0; i < 4; i++) {
#pragma unroll
            for (int r = 0; r < 4; r++) {
                float ss = 0.f, sd = 0.f;
#pragma unroll
                for (int j = 0; j < 4; j++) {
                    int c = wc + j * 16 + lm;
                    ss += acc[i][j][r] * wsp[hh * HEAD_DIM + c];
                    sd += acc[i][j][r] * wdp[hh * HEAD_DIM + c];
                }
#pragma unroll
                for (int off = 1; off < 16; off <<= 1) {
                    ss += __shfl_xor(ss, off);
                    sd += __shfl_xor(sd, off);
                }
                if (lm == 0) {
                    int rl = wr + i * 16 + quad * 4 + r;
                    attbuf[rl][half2]     = ss;
                    attbuf[rl][half2 + 1] = sd;
                }
            }
        }
        __syncthreads();
        if (tid < 128) {
            int grl = m0 + tid;
            if (grl < Mv) {
                int gr = rowlist ? rowlist[grl] : grl;
                asrc[(size_t)gr * 8 + h] = attbuf[tid][0] + attbuf[tid][2];
                adst[(size_t)gr * 8 + h] = attbuf[tid][1] + attbuf[tid][3];
            }
        }
    }

    // C store: C/D layout col=lane&15, row=quad*4+reg
#pragma unroll
    for (int i = 0; i < 4; i++) {
        int grb = wr + i * 16 + quad * 4;
#pragma unroll
        for (int j = 0; j < 4; j++) {
            int gc = n0 + wc + j * 16 + lm;
            if (gc < N) {
#pragma unroll
                for (int r = 0; r < 4; r++) {
                    int grl = m0 + grb + r;
                    if (grl < Mv) {
                        int gr = rowlist ? rowlist[grl] : grl;
                        float v = acc[i][j][r];
                        if (out_bf16) {
                            ((unsigned short*)Cout)[(size_t)gr * N + gc] = f2bf(v);
                        } else {
                            float b = bias ? bias[gc] : 0.0f;
                            ((float*)Cout)[(size_t)gr * N + gc] = v + b;
                        }
                    }
                }
            }
        }
    }
}

// ---------------- compact-row fp32 -> bf16 convert (grid-stride) ----------------
__global__ void cvt_rows_kernel(const float* __restrict__ X, const int* __restrict__ list,
                                const int* __restrict__ countp, unsigned short* __restrict__ Y)
{
    int n0 = countp[0];
    int col = (threadIdx.x & 127) * 8;
    for (int i = blockIdx.x * 2 + (threadIdx.x >> 7); i < n0; i += gridDim.x * 2) {
        const floatx4* xp = (const floatx4*)(X + (size_t)list[i] * IN_FEATS + col);
        floatx4 f0 = xp[0], f1 = xp[1];
        short8 v;
        v[0] = (short)f2bf(f0[0]); v[1] = (short)f2bf(f0[1]);
        v[2] = (short)f2bf(f0[2]); v[3] = (short)f2bf(f0[3]);
        v[4] = (short)f2bf(f1[0]); v[5] = (short)f2bf(f1[1]);
        v[6] = (short)f2bf(f1[2]); v[7] = (short)f2bf(f1[3]);
        *(short8*)(Y + (size_t)i * IN_FEATS + col) = v;
    }
}

// ---------------- combined CSR build (both edge types in one chain) ----------------
// cnt2 / rowptrc index space: type1 dst d -> d, type2 dst d -> N_NODES + d.
// srcsc holds type-1 edges then type-2 edges (prefix over 2N buckets).
__global__ void hist2_kernel(const int* __restrict__ e1d, const int* __restrict__ e2d,
                             int* __restrict__ cnt2, int E)
{
    int e = blockIdx.x * blockDim.x + threadIdx.x;
    if (e < E) {
        atomicAdd(&cnt2[e1d[e]], 1);
        atomicAdd(&cnt2[N_NODES + e2d[e]], 1);
    }
}

__global__ void scan1_kernel(const int* __restrict__ cnt, int* __restrict__ partial,
                             int* __restrict__ chunksum, int n)
{
    __shared__ int sm[256];
    int t = threadIdx.x;
    int i = blockIdx.x * 256 + t;
    int v = (i < n) ? cnt[i] : 0;
    sm[t] = v; __syncthreads();
    int val = v;
#pragma unroll
    for (int off = 1; off < 256; off <<= 1) {
        int u = (t >= off) ? sm[t - off] : 0;
        __syncthreads();
        val += u; sm[t] = val;
        __syncthreads();
    }
    if (i < n) partial[i] = val - v;
    if (t == 255) chunksum[blockIdx.x] = val;
}

__global__ void scan2_kernel(int* __restrict__ chunksum, int n)
{
    __shared__ int sm[1024];
    int t = threadIdx.x;
    int v = (t < n) ? chunksum[t] : 0;
    sm[t] = v; __syncthreads();
    int val = v;
#pragma unroll
    for (int off = 1; off < 1024; off <<= 1) {
        int u = (t >= off) ? sm[t - off] : 0;
        __syncthreads();
        val += u; sm[t] = val;
        __syncthreads();
    }
    if (t < n) chunksum[t] = val - v;
}

__global__ void scan3c_kernel(const int* __restrict__ partial, const int* __restrict__ chunksum,
                              int* __restrict__ rowptrc, int* __restrict__ cursor, int n, int Etot)
{
    int i = blockIdx.x * 256 + threadIdx.x;
    if (i < n) {
        int r = partial[i] + chunksum[i >> 8];
        rowptrc[i] = r;
        cursor[i] = r;
    }
    if (i == 0) rowptrc[n] = Etot;
}

__global__ void fill2_kernel(const int* __restrict__ e1s, const int* __restrict__ e1d,
                             const int* __restrict__ e2s, const int* __restrict__ e2d,
                             int* __restrict__ cursor, int* __restrict__ srcsc, int E)
{
    int e = blockIdx.x * blockDim.x + threadIdx.x;
    if (e < E) {
        int p = atomicAdd(&cursor[e1d[e]], 1);
        srcsc[p] = e1s[e];
        int q = atomicAdd(&cursor[N_NODES + e2d[e]], 1);
        srcsc[q] = e2s[e];
    }
}

// ---------------- frontier marking / combined compaction ----------------
// flagbuf: F1 flags at [0,N), F0 flags at [N,2N).
__global__ void mark1_kernel(const int* __restrict__ e1s, const int* __restrict__ e1d,
                             const int* __restrict__ e2s, const int* __restrict__ e2d,
                             int* __restrict__ flag1, int E)
{
    int e = blockIdx.x * blockDim.x + threadIdx.x;
    if (e >= E) return;
    if (e < BATCH) flag1[e] = 1;
    if (e1d[e] < BATCH) flag1[e1s[e]] = 1;
    if (e2d[e] < BATCH) flag1[e2s[e]] = 1;
}

__global__ void mark0_kernel(const int* __restrict__ e1s, const int* __restrict__ e1d,
                             const int* __restrict__ e2s, const int* __restrict__ e2d,
                             const int* __restrict__ flag1, int* __restrict__ flag0,
                             int E, int Nn)
{
    int i = blockIdx.x * blockDim.x + threadIdx.x;
    if (i < E) {
        if (flag1[e1d[i]]) flag0[e1s[i]] = 1;
        if (flag1[e2d[i]]) flag0[e2s[i]] = 1;
    }
    if (i < Nn && flag1[i]) flag0[i] = 1;
}

// compact both frontiers out of one 2N scan; count1 = prefix at index N.
__global__ void compactF_kernel(const int* __restrict__ flag, const int* __restrict__ partial,
                                const int* __restrict__ chunksum,
                                int* __restrict__ list1, int* __restrict__ list0,
                                int* __restrict__ count1, int* __restrict__ count0)
{
    int i = blockIdx.x * 256 + threadIdx.x;
    if (i >= 2 * N_NODES) return;
    int total1 = partial[N_NODES] + chunksum[N_NODES >> 8];
    int pos = partial[i] + chunksum[i >> 8];
    if (i < N_NODES) {
        if (flag[i]) list1[pos] = i;
        if (i == 0) count1[0] = total1;
    } else {
        if (flag[i]) list0[pos - total1] = i - N_NODES;
        if (i == 2 * N_NODES - 1) count0[0] = pos + flag[i] - total1;
    }
}

// ---------------- fused dual-edge-type gather (grid-stride) ----------------
// For dst-slot i (node d = dlist ? dlist[i] : i): softmax aggregation over
// type 1 (heads 0-3, H cols 0-511, CSR bucket d) and type 2 (heads 4-7,
// H cols 512-1023, CSR bucket N_NODES+d), +b1+b2, optional lrelu(0.01).
// H stride 1024 (node-indexed), Out stride 512 (slot-indexed, dense).
__global__ void gather2_kernel(const int* __restrict__ rowptrc, const int* __restrict__ srcsc,
                               const float* __restrict__ asrc, const float* __restrict__ adst,
                               const unsigned short* __restrict__ H,
                               const float* __restrict__ b1, const float* __restrict__ b2,
                               const int* __restrict__ dlist, const int* __restrict__ dcountp,
                               unsigned short* __restrict__ Out, int ndst, int do_lrelu)
{
    int nd = dcountp ? dcountp[0] : ndst;
    int lane = threadIdx.x & 63;
    int head = lane >> 4;      // 128 cols per head = 16 lanes * 8
    int col = lane * 8;
    for (int i = blockIdx.x * 4 + (threadIdx.x >> 6); i < nd; i += gridDim.x * 4) {
        int d = dlist ? dlist[i] : i;
        float r[8], acc[8];
        // ---- edge type 1: heads 0-3, H cols [0,512) ----
        {
            int beg = rowptrc[d], end = rowptrc[d + 1];
            float ad = adst[(size_t)d * 8 + head];
            float den = 0.f;
#pragma unroll
            for (int k = 0; k < 8; k++) acc[k] = 0.f;
            for (int j = beg; j < end; j++) {
                int s = srcsc[j];
                float v = asrc[(size_t)s * 8 + head] + ad;
                v = v > 0.f ? v : 0.2f * v;
                float ex = expf(v);
                den += ex;
                short8 hv = *(const short8*)(H + (size_t)s * 1024 + col);
#pragma unroll
                for (int k = 0; k < 8; k++) acc[k] += ex * bf2f((unsigned short)hv[k]);
            }
            float inv = den > 0.f ? 1.f / den : 0.f;
#pragma unroll
            for (int k = 0; k < 8; k++) r[k] = acc[k] * inv;
        }
        // ---- edge type 2: heads 4-7, H cols [512,1024) ----
        {
            int beg = rowptrc[N_NODES + d], end = rowptrc[N_NODES + d + 1];
            float ad = adst[(size_t)d * 8 + 4 + head];
            float den = 0.f;
#pragma unroll
            for (int k = 0; k < 8; k++) acc[k] = 0.f;
            for (int j = beg; j < end; j++) {
                int s = srcsc[j];
                float v = asrc[(size_t)s * 8 + 4 + head] + ad;
                v = v > 0.f ? v : 0.2f * v;
                float ex = expf(v);
                den += ex;
                short8 hv = *(const short8*)(H + (size_t)s * 1024 + 512 + col);
#pragma unroll
                for (int k = 0; k < 8; k++) acc[k] += ex * bf2f((unsigned short)hv[k]);
            }
            float inv = den > 0.f ? 1.f / den : 0.f;
#pragma unroll
            for (int k = 0; k < 8; k++) r[k] += acc[k] * inv;
        }
        short8 o;
#pragma unroll
        for (int k = 0; k < 8; k++) {
            float f = r[k] + b1[col + k] + b2[col + k];
            if (do_lrelu) f = f > 0.f ? f : 0.01f * f;
            o[k] = (short)f2bf(f);
        }
        *(short8*)(Out + (size_t)i * 512 + col) = o;
    }
}

// fused pair transpose: WT[n][k] = (n<Nh ? Wa : Wb)[k][n-...], W is [K][Nh] fp32.
__global__ void transpose2_kernel(const float* __restrict__ Wa, const float* __restrict__ Wb,
                                  unsigned short* __restrict__ WT, int K, int Nh)
{
    int k = blockIdx.x * 256 + threadIdx.x;
    if (k >= K) return;
    int n = blockIdx.y;
    const float* W = (n < Nh) ? Wa : Wb;
    int nn = (n < Nh) ? n : n - Nh;
    WT[(size_t)n * K + k] = f2bf(W[(size_t)k * Nh + nn]);
}

extern "C" void kernel_launch(void* const* d_in, const int* in_sizes, int n_in,
                              void* d_out, int out_size, void* d_ws, size_t ws_size,
                              hipStream_t stream)
{
    const float* x    = (const float*)d_in[0];
    const int* e1s    = (const int*)d_in[1];
    const int* e1d    = (const int*)d_in[2];
    const int* e2s    = (const int*)d_in[3];
    const int* e2d    = (const int*)d_in[4];
    const float* w0a  = (const float*)d_in[6];
    const float* as0a = (const float*)d_in[7];
    const float* ad0a = (const float*)d_in[8];
    const float* b0a  = (const float*)d_in[9];
    const float* w0b  = (const float*)d_in[10];
    const float* as0b = (const float*)d_in[11];
    const float* ad0b = (const float*)d_in[12];
    const float* b0b  = (const float*)d_in[13];
    const float* w1a  = (const float*)d_in[14];
    const float* as1a = (const float*)d_in[15];
    const float* ad1a = (const float*)d_in[16];
    const float* b1a  = (const float*)d_in[17];
    const float* w1b  = (const float*)d_in[18];
    const float* as1b = (const float*)d_in[19];
    const float* ad1b = (const float*)d_in[20];
    const float* b1b  = (const float*)d_in[21];
    const float* linw = (const float*)d_in[22];
    const float* linb = (const float*)d_in[23];
    float* out = (float*)d_out;
    (void)in_sizes; (void)n_in; (void)out_size;

    char* ws = (char*)d_ws;
    size_t off = 0;
    auto carve = [&](size_t bytes) -> void* {
        void* p = ws + off; off += (bytes + 255) & ~(size_t)255; return p;
    };
    unsigned short* WT0 = (unsigned short*)carve((size_t)2 * H_FEATS * IN_FEATS * 2); // [1024][1024]
    unsigned short* WT1 = (unsigned short*)carve((size_t)2 * H_FEATS * H_FEATS * 2);  // [1024][512]
    unsigned short* WTl = (unsigned short*)carve((size_t)N_CLASSES * H_FEATS * 2);
    unsigned short* Hbf = (unsigned short*)carve((size_t)N_NODES * 1024 * 2);  // GEMM out, node-indexed
    unsigned short* H1c = (unsigned short*)carve((size_t)N_NODES * H_FEATS * 2); // F1-compact layer-0 out
    unsigned short* h2s = (unsigned short*)carve((size_t)BATCH * H_FEATS * 2);
    float* asrc = (float*)carve((size_t)N_NODES * 8 * 4);
    float* adst = (float*)carve((size_t)N_NODES * 8 * 4);
    int* rowptrc = (int*)carve((size_t)(2 * N_NODES + 1) * 4);
    int* srcsc   = (int*)carve((size_t)2 * N_EDGES * 4);
    int* cnt2    = (int*)carve((size_t)2 * N_NODES * 4);   // histogram, then cursor
    int* partial = (int*)carve((size_t)2 * N_NODES * 4);
    int* chunksum= (int*)carve((size_t)1024 * 4);
    int* flagbuf = (int*)carve((size_t)2 * N_NODES * 4);   // [flag1 | flag0]
    int* list1   = (int*)carve((size_t)N_NODES * 4);
    int* list0   = (int*)carve((size_t)N_NODES * 4);
    int* count1  = (int*)carve(256);
    int* count0  = (int*)carve(256);
    // compact bf16 A for layer 0 (worst case all nodes): only if ws allows.
    // Decision depends only on ws_size -> identical every call (capture-safe).
    unsigned short* xc = nullptr;
    {
        size_t need = (size_t)N_NODES * IN_FEATS * 2;
        if (off + need <= ws_size) xc = (unsigned short*)carve(need);
    }

    const int NCHUNK2 = (2 * N_NODES + 255) / 256;        // 782
    const int MT8 = (((N_NODES + 127) / 128) + 7) & ~7;   // 784, multiple of 8 for swizzle
    const int EG = (N_EDGES + 255) / 256;                 // 782

    // --- fused weight transposes ---
    transpose2_kernel<<<dim3(IN_FEATS / 256, 2 * H_FEATS), 256, 0, stream>>>(w0a, w0b, WT0, IN_FEATS, H_FEATS);
    transpose2_kernel<<<dim3(H_FEATS / 256, 2 * H_FEATS), 256, 0, stream>>>(w1a, w1b, WT1, H_FEATS, H_FEATS);
    transpose2_kernel<<<dim3(H_FEATS / 256, N_CLASSES), 256, 0, stream>>>(linw, linw, WTl, H_FEATS, N_CLASSES);

    // --- frontier F1 / F0 (raw edge lists, no CSR dependency) ---
    hipMemsetAsync(flagbuf, 0, (size_t)2 * N_NODES * 4, stream);
    mark1_kernel<<<EG, 256, 0, stream>>>(e1s, e1d, e2s, e2d, flagbuf, N_EDGES);
    mark0_kernel<<<EG, 256, 0, stream>>>(e1s, e1d, e2s, e2d, flagbuf, flagbuf + N_NODES,
                                         N_EDGES, N_NODES);
    scan1_kernel<<<NCHUNK2, 256, 0, stream>>>(flagbuf, partial, chunksum, 2 * N_NODES);
    scan2_kernel<<<1, 1024, 0, stream>>>(chunksum, NCHUNK2);
    compactF_kernel<<<NCHUNK2, 256, 0, stream>>>(flagbuf, partial, chunksum,
                                                 list1, list0, count1, count0);

    // --- combined CSR build (both edge types, one scan chain) ---
    hipMemsetAsync(cnt2, 0, (size_t)2 * N_NODES * 4, stream);
    hist2_kernel<<<EG, 256, 0, stream>>>(e1d, e2d, cnt2, N_EDGES);
    scan1_kernel<<<NCHUNK2, 256, 0, stream>>>(cnt2, partial, chunksum, 2 * N_NODES);
    scan2_kernel<<<1, 1024, 0, stream>>>(chunksum, NCHUNK2);
    scan3c_kernel<<<NCHUNK2, 256, 0, stream>>>(partial, chunksum, rowptrc, cnt2,
                                               2 * N_NODES, 2 * N_EDGES);
    fill2_kernel<<<EG, 256, 0, stream>>>(e1s, e1d, e2s, e2d, cnt2, srcsc, N_EDGES);

    // --- compact x rows -> bf16 (F0 only) ---
    if (xc) {
        cvt_rows_kernel<<<1024, 256, 0, stream>>>(x, list0, count0, xc);
    }

    // --- layer 0: fused N=1024 GEMM over F0 rows, gather over F1 dsts ---
    if (xc) {
        gemm_kernel<<<MT8 * 8, 256, 0, stream>>>(xc, 0, 1, WT0, Hbf, nullptr,
                                                 as0a, ad0a, as0b, ad0b, asrc, adst,
                                                 list0, count0,
                                                 N_NODES, 1024, 8, IN_FEATS, 1);
    } else {
        gemm_kernel<<<MT8 * 8, 256, 0, stream>>>(x, 1, 0, WT0, Hbf, nullptr,
                                                 as0a, ad0a, as0b, ad0b, asrc, adst,
                                                 list0, count0,
                                                 N_NODES, 1024, 8, IN_FEATS, 1);
    }
    gather2_kernel<<<2048, 256, 0, stream>>>(rowptrc, srcsc, asrc, adst, Hbf, b0a, b0b,
                                             list1, count1, H1c, N_NODES, 1);

    // --- layer 1: compact GEMM over F1 rows (scatter into Hbf), gather over BATCH ---
    gemm_kernel<<<MT8 * 8, 256, 0, stream>>>(H1c, 0, 1, WT1, Hbf, nullptr,
                                             as1a, ad1a, as1b, ad1b, asrc, adst,
                                             list1, count1,
                                             N_NODES, 1024, 8, H_FEATS, 1);
    gather2_kernel<<<256, 256, 0, stream>>>(rowptrc, srcsc, asrc, adst, Hbf, b1a, b1b,
                                            nullptr, nullptr, h2s, BATCH, 0);

    // --- classification head ---
    const int HN_T = (N_CLASSES + 127) / 128;   // 24
    gemm_kernel<<<(BATCH / 128) * HN_T, 256, 0, stream>>>(h2s, 0, 0, WTl, out, linb,
                                                          nullptr, nullptr, nullptr, nullptr,
                                                          nullptr, nullptr, nullptr, nullptr,
                                                          BATCH, N_CLASSES, HN_T, H_FEATS, 0);
}

// Round 5
// 748.973 us; speedup vs baseline: 2.1547x; 1.0358x over previous
//
#include <hip/hip_runtime.h>

#define N_NODES 100000
#define N_EDGES 200000
#define IN_FEATS 1024
#define H_FEATS 512
#define N_HEADS 4
#define HEAD_DIM 128
#define N_CLASSES 2983
#define BATCH 1024
#define NCHUNK2 782   // ceil(2*N_NODES / 256)

typedef __attribute__((ext_vector_type(8))) short short8;
typedef __attribute__((ext_vector_type(4))) float floatx4;

typedef __attribute__((address_space(1))) void global_as_void;
typedef __attribute__((address_space(3))) void lds_as_void;

__device__ __forceinline__ float bf2f(unsigned short u) {
    union { unsigned int i; float f; } x; x.i = ((unsigned int)u) << 16; return x.f;
}
__device__ __forceinline__ unsigned short f2bf(float f) {
    union { float f; unsigned int i; } x; x.f = f;
    unsigned int r = x.i + 0x7FFFu + ((x.i >> 16) & 1u);
    return (unsigned short)(r >> 16);
}
__device__ __forceinline__ void load_lds16(const void* g, void* l) {
    __builtin_amdgcn_global_load_lds((const global_as_void*)g, (lds_as_void*)l, 16, 0, 0);
}

// ---------------- GEMM ----------------
// C[M,N] = A @ BT^T.  A: bf16 (a_fp32=0) or fp32 (a_fp32=1).
// Row indirection: countp = device row count (null -> M); rowlist maps
// compact row -> node id.  a_dense=1: A stored compact (dense index);
// C stores + att logit stores scatter via rowlist.  a_dense=0: A via rowlist.
// All staging addresses hoisted out of the K-loop (rowlist read once).
// XCD swizzle (n_tiles==8): mt = (bid&7) + 8*(bid>>6), nt = (bid>>3)&7 ->
// one XCD walks all 8 n-tiles of its m-tile (A-tile L2-resident).
// att epilogue: head h = nt; h<4 -> att_s/att_d, h>=4 -> att_s2/att_d2.
// Row logits: each wave covers HALF the head cols (wc=0 -> 0-63, wc=64 ->
// 64-127); the two wave-halves are summed in LDS (attbuf) before ONE
// plain store per (node,h).
// LDS swizzle: 16B slot c of row r holds global k-chunk c ^ ((r>>1)&3).
__global__ __launch_bounds__(256, 3)
void gemm_kernel(const void* __restrict__ Ain, int a_fp32, int a_dense,
                 const unsigned short* __restrict__ BT,
                 void* __restrict__ Cout, const float* __restrict__ bias,
                 const float* __restrict__ att_s, const float* __restrict__ att_d,
                 const float* __restrict__ att_s2, const float* __restrict__ att_d2,
                 float* __restrict__ asrc, float* __restrict__ adst,
                 const int* __restrict__ rowlist, const int* __restrict__ countp,
                 int M, int N, int n_tiles, int K, int out_bf16)
{
    __shared__ __attribute__((aligned(16))) unsigned short As[128 * 32];
    __shared__ __attribute__((aligned(16))) unsigned short Bs[128 * 32];
    __shared__ float attbuf[128][4];   // [row][{ss,sd} x {half0,half1}]
    const int tid  = threadIdx.x;
    const int lane = tid & 63;
    const int wave = tid >> 6;
    const int bid = blockIdx.x;
    int mt, nt;
    if (n_tiles == 8) {
        mt = (bid & 7) + ((bid >> 6) << 3);
        nt = (bid >> 3) & 7;
    } else {
        mt = bid / n_tiles;
        nt = bid - mt * n_tiles;
    }
    const int m0 = mt * 128;
    const int n0 = nt * 128;
    int Mv = M;
    if (countp) Mv = countp[0];
    if (m0 >= Mv) return;           // uniform across block: safe before barriers
    const int wr = (wave >> 1) * 64;
    const int wc = (wave & 1) * 64;
    const int lm = lane & 15;
    const int quad = lane >> 4;

    auto arow = [&](int r) -> int {
        int gr = m0 + r; if (gr > Mv - 1) gr = Mv - 1;
        if (rowlist && !a_dense) gr = rowlist[gr];
        return gr;
    };

    // ---- hoisted staging addresses (invariant over K) ----
    const float* a_fp[2];
    const unsigned short* a_bf[2];
    char* a_lds[2];
    const unsigned short* b_bf[2];
    char* b_lds[2];
    if (a_fp32) {
        int row = tid >> 2, slot = tid & 3;
#pragma unroll
        for (int p = 0; p < 2; p++) {
            int r = p * 64 + row;
            a_fp[p] = (const float*)Ain + (size_t)arow(r) * K + (slot ^ ((r >> 1) & 3)) * 8;
        }
    } else {
#pragma unroll
        for (int i = 0; i < 2; i++) {
            int r = wave * 32 + i * 16 + (lane >> 2);
            a_bf[i] = (const unsigned short*)Ain + (size_t)arow(r) * K
                    + ((lane & 3) ^ ((r >> 1) & 3)) * 8;
            a_lds[i] = (char*)As + (size_t)(wave * 2 + i) * 1024;
        }
    }
#pragma unroll
    for (int i = 0; i < 2; i++) {
        int r = wave * 32 + i * 16 + (lane >> 2);
        int gn = n0 + r; if (gn > N - 1) gn = N - 1;
        b_bf[i] = BT + (size_t)gn * K + ((lane & 3) ^ ((r >> 1) & 3)) * 8;
        b_lds[i] = (char*)Bs + (size_t)(wave * 2 + i) * 1024;
    }

    floatx4 acc[4][4];
#pragma unroll
    for (int i = 0; i < 4; i++)
#pragma unroll
        for (int j = 0; j < 4; j++) acc[i][j] = (floatx4)0.0f;

    for (int k0 = 0; k0 < K; k0 += 32) {
        __syncthreads();
        if (a_fp32) {
            int row = tid >> 2, slot = tid & 3;
#pragma unroll
            for (int p = 0; p < 2; p++) {
                int r = p * 64 + row;
                floatx4 f0 = *(const floatx4*)(a_fp[p] + k0);
                floatx4 f1 = *(const floatx4*)(a_fp[p] + k0 + 4);
                short8 v;
                v[0] = (short)f2bf(f0[0]); v[1] = (short)f2bf(f0[1]);
                v[2] = (short)f2bf(f0[2]); v[3] = (short)f2bf(f0[3]);
                v[4] = (short)f2bf(f1[0]); v[5] = (short)f2bf(f1[1]);
                v[6] = (short)f2bf(f1[2]); v[7] = (short)f2bf(f1[3]);
                *(short8*)&As[r * 32 + slot * 8] = v;
            }
        } else {
#pragma unroll
            for (int i = 0; i < 2; i++)
                load_lds16(a_bf[i] + k0, a_lds[i]);
        }
#pragma unroll
        for (int i = 0; i < 2; i++)
            load_lds16(b_bf[i] + k0, b_lds[i]);
        __syncthreads();
        short8 af[4], bfr[4];
#pragma unroll
        for (int i = 0; i < 4; i++) {
            int ra = wr + i * 16 + lm;
            af[i] = *(const short8*)&As[ra * 32 + ((quad ^ ((ra >> 1) & 3)) << 3)];
            int rb = wc + i * 16 + lm;
            bfr[i] = *(const short8*)&Bs[rb * 32 + ((quad ^ ((rb >> 1) & 3)) << 3)];
        }
#pragma unroll
        for (int i = 0; i < 4; i++)
#pragma unroll
            for (int j = 0; j < 4; j++)
                acc[i][j] = __builtin_amdgcn_mfma_f32_16x16x32_bf16(af[i], bfr[j], acc[i][j], 0, 0, 0);
    }

    // fused attention logits (this block covers exactly one head's 128 cols;
    // each wave holds half the cols -> combine the two halves via LDS).
    if (att_s) {
        const int h = nt;
        const float* wsp = (h < 4) ? att_s : att_s2;
        const float* wdp = (h < 4) ? att_d : att_d2;
        const int hh = h & 3;
        const int half2 = (wc >> 6) * 2;   // 0 or 2
#pragma unroll
        for (int i = 0; i < 4; i++) {
#pragma unroll
            for (int r = 0; r < 4; r++) {
                float ss = 0.f, sd = 0.f;
#pragma unroll
                for (int j = 0; j < 4; j++) {
                    int c = wc + j * 16 + lm;
                    ss += acc[i][j][r] * wsp[hh * HEAD_DIM + c];
                    sd += acc[i][j][r] * wdp[hh * HEAD_DIM + c];
                }
#pragma unroll
                for (int off = 1; off < 16; off <<= 1) {
                    ss += __shfl_xor(ss, off);
                    sd += __shfl_xor(sd, off);
                }
                if (lm == 0) {
                    int rl = wr + i * 16 + quad * 4 + r;
                    attbuf[rl][half2]     = ss;
                    attbuf[rl][half2 + 1] = sd;
                }
            }
        }
        __syncthreads();
        if (tid < 128) {
            int grl = m0 + tid;
            if (grl < Mv) {
                int gr = rowlist ? rowlist[grl] : grl;
                asrc[(size_t)gr * 8 + h] = attbuf[tid][0] + attbuf[tid][2];
                adst[(size_t)gr * 8 + h] = attbuf[tid][1] + attbuf[tid][3];
            }
        }
    }

    // C store: C/D layout col=lane&15, row=quad*4+reg
#pragma unroll
    for (int i = 0; i < 4; i++) {
        int grb = wr + i * 16 + quad * 4;
#pragma unroll
        for (int j = 0; j < 4; j++) {
            int gc = n0 + wc + j * 16 + lm;
            if (gc < N) {
#pragma unroll
                for (int r = 0; r < 4; r++) {
                    int grl = m0 + grb + r;
                    if (grl < Mv) {
                        int gr = rowlist ? rowlist[grl] : grl;
                        float v = acc[i][j][r];
                        if (out_bf16) {
                            ((unsigned short*)Cout)[(size_t)gr * N + gc] = f2bf(v);
                        } else {
                            float b = bias ? bias[gc] : 0.0f;
                            ((float*)Cout)[(size_t)gr * N + gc] = v + b;
                        }
                    }
                }
            }
        }
    }
}

// ---------------- prep1: transposes + mark1 + hist2 (after one memset) ----------------
// WT0[n][k] = bf16((n<512 ? w0a : w0b)[k][n&511]),  n<1024, k<1024
// WT1[n][k] = bf16((n<512 ? w1a : w1b)[k][n&511]),  n<1024, k<512
// WTl[n][k] = bf16(linw[k][n]),                     n<N_CLASSES, k<512
// flag1[seed|src-of-edge-into-seed] = 1; cnt2 histogram over 2N dst buckets.
__global__ void prep1_kernel(const float* __restrict__ w0a, const float* __restrict__ w0b,
                             const float* __restrict__ w1a, const float* __restrict__ w1b,
                             const float* __restrict__ linw,
                             unsigned short* __restrict__ WT0, unsigned short* __restrict__ WT1,
                             unsigned short* __restrict__ WTl,
                             const int* __restrict__ e1s, const int* __restrict__ e1d,
                             const int* __restrict__ e2s, const int* __restrict__ e2d,
                             int* __restrict__ flag1, int* __restrict__ cnt2)
{
    const int gsz = gridDim.x * 256;
    const int gid = blockIdx.x * 256 + threadIdx.x;
    for (int i = gid; i < 1024 * 1024; i += gsz) {
        int n = i >> 10, k = i & 1023;
        const float* W = (n < 512) ? w0a : w0b;
        WT0[i] = f2bf(W[(size_t)k * 512 + (n & 511)]);
    }
    for (int i = gid; i < 1024 * 512; i += gsz) {
        int n = i >> 9, k = i & 511;
        const float* W = (n < 512) ? w1a : w1b;
        WT1[i] = f2bf(W[(size_t)k * 512 + (n & 511)]);
    }
    for (int i = gid; i < N_CLASSES * 512; i += gsz) {
        int n = i >> 9, k = i & 511;
        WTl[i] = f2bf(linw[(size_t)k * N_CLASSES + n]);
    }
    for (int e = gid; e < N_EDGES; e += gsz) {
        if (e < BATCH) flag1[e] = 1;
        int d1 = e1d[e], d2 = e2d[e];
        if (d1 < BATCH) flag1[e1s[e]] = 1;
        if (d2 < BATCH) flag1[e2s[e]] = 1;
        atomicAdd(&cnt2[d1], 1);
        atomicAdd(&cnt2[N_NODES + d2], 1);
    }
}

// F0 = srcs of edges whose dst is in F1, plus F1 itself.
__global__ void mark0_kernel(const int* __restrict__ e1s, const int* __restrict__ e1d,
                             const int* __restrict__ e2s, const int* __restrict__ e2d,
                             const int* __restrict__ flag1, int* __restrict__ flag0,
                             int E, int Nn)
{
    int i = blockIdx.x * blockDim.x + threadIdx.x;
    if (i < E) {
        if (flag1[e1d[i]]) flag0[e1s[i]] = 1;
        if (flag1[e2d[i]]) flag0[e2s[i]] = 1;
    }
    if (i < Nn && flag1[i]) flag0[i] = 1;
}

// ---------------- scanA: per-chunk scan of flagbuf(2N) AND cnt2(2N) ----------------
// blocks [0,NCHUNK2): flagbuf -> partialF/chunkF; [NCHUNK2,2*NCHUNK2): cnt2 -> partialC/chunkC
__global__ void scanA_kernel(const int* __restrict__ flagbuf, const int* __restrict__ cnt2,
                             int* __restrict__ partialF, int* __restrict__ chunkF,
                             int* __restrict__ partialC, int* __restrict__ chunkC)
{
    __shared__ int sm[256];
    int b = blockIdx.x;
    const int* src; int* pdst; int* cdst; int cb;
    if (b < NCHUNK2) { src = flagbuf; pdst = partialF; cdst = chunkF; cb = b; }
    else             { src = cnt2;    pdst = partialC; cdst = chunkC; cb = b - NCHUNK2; }
    int t = threadIdx.x;
    int i = cb * 256 + t;
    int v = (i < 2 * N_NODES) ? src[i] : 0;
    sm[t] = v; __syncthreads();
    int val = v;
#pragma unroll
    for (int off = 1; off < 256; off <<= 1) {
        int u = (t >= off) ? sm[t - off] : 0;
        __syncthreads();
        val += u; sm[t] = val;
        __syncthreads();
    }
    if (i < 2 * N_NODES) pdst[i] = val - v;
    if (t == 255) cdst[cb] = val;
}

// scanB: single block exclusive-scans chunkF then chunkC (NCHUNK2 <= 1024 each)
__global__ void scanB_kernel(int* __restrict__ chunkF, int* __restrict__ chunkC, int n)
{
    __shared__ int sm[1024];
    int t = threadIdx.x;
#pragma unroll
    for (int pass = 0; pass < 2; pass++) {
        int* c = pass ? chunkC : chunkF;
        int v = (t < n) ? c[t] : 0;
        sm[t] = v; __syncthreads();
        int val = v;
#pragma unroll
        for (int off = 1; off < 1024; off <<= 1) {
            int u = (t >= off) ? sm[t - off] : 0;
            __syncthreads();
            val += u; sm[t] = val;
            __syncthreads();
        }
        if (t < n) c[t] = val - v;
        __syncthreads();
    }
}

// finalize: compact F1/F0 lists + counts (flag side) AND rowptrc/cursor (CSR side)
__global__ void finalize_kernel(const int* __restrict__ flagbuf,
                                const int* __restrict__ partialF, const int* __restrict__ chunkF,
                                const int* __restrict__ partialC, const int* __restrict__ chunkC,
                                int* __restrict__ list1, int* __restrict__ list0,
                                int* __restrict__ count1, int* __restrict__ count0,
                                int* __restrict__ rowptrc, int* __restrict__ cursor)
{
    int i = blockIdx.x * 256 + threadIdx.x;
    if (i >= 2 * N_NODES) return;
    // CSR side
    int r = partialC[i] + chunkC[i >> 8];
    rowptrc[i] = r;
    cursor[i] = r;
    if (i == 0) rowptrc[2 * N_NODES] = 2 * N_EDGES;
    // frontier side
    int total1 = partialF[N_NODES] + chunkF[N_NODES >> 8];
    int pos = partialF[i] + chunkF[i >> 8];
    int f = flagbuf[i];
    if (i < N_NODES) {
        if (f) list1[pos] = i;
        if (i == 0) count1[0] = total1;
    } else {
        if (f) list0[pos - total1] = i - N_NODES;
        if (i == 2 * N_NODES - 1) count0[0] = pos + f - total1;
    }
}

// fill CSR srcs + compact-row x->bf16 convert (both depend only on finalize)
__global__ void fill_cvt_kernel(const int* __restrict__ e1s, const int* __restrict__ e1d,
                                const int* __restrict__ e2s, const int* __restrict__ e2d,
                                int* __restrict__ cursor, int* __restrict__ srcsc,
                                const float* __restrict__ X, const int* __restrict__ list0,
                                const int* __restrict__ count0, unsigned short* __restrict__ Y)
{
    const int gsz = gridDim.x * 256;
    const int gid = blockIdx.x * 256 + threadIdx.x;
    for (int e = gid; e < N_EDGES; e += gsz) {
        int p = atomicAdd(&cursor[e1d[e]], 1);
        srcsc[p] = e1s[e];
        int q = atomicAdd(&cursor[N_NODES + e2d[e]], 1);
        srcsc[q] = e2s[e];
    }
    int n0 = count0[0];
    int col = (threadIdx.x & 127) * 8;
    for (int i = blockIdx.x * 2 + (threadIdx.x >> 7); i < n0; i += gridDim.x * 2) {
        const floatx4* xp = (const floatx4*)(X + (size_t)list0[i] * IN_FEATS + col);
        floatx4 f0 = xp[0], f1 = xp[1];
        short8 v;
        v[0] = (short)f2bf(f0[0]); v[1] = (short)f2bf(f0[1]);
        v[2] = (short)f2bf(f0[2]); v[3] = (short)f2bf(f0[3]);
        v[4] = (short)f2bf(f1[0]); v[5] = (short)f2bf(f1[1]);
        v[6] = (short)f2bf(f1[2]); v[7] = (short)f2bf(f1[3]);
        *(short8*)(Y + (size_t)i * IN_FEATS + col) = v;
    }
}

// ---------------- fused dual-edge-type gather (grid-stride) ----------------
// For dst-slot i (node d = dlist ? dlist[i] : i): softmax aggregation over
// type 1 (heads 0-3, H cols 0-511, CSR bucket d) and type 2 (heads 4-7,
// H cols 512-1023, CSR bucket N_NODES+d), +b1+b2, optional lrelu(0.01).
// H stride 1024 (node-indexed), Out stride 512 (slot-indexed, dense).
__global__ void gather2_kernel(const int* __restrict__ rowptrc, const int* __restrict__ srcsc,
                               const float* __restrict__ asrc, const float* __restrict__ adst,
                               const unsigned short* __restrict__ H,
                               const float* __restrict__ b1, const float* __restrict__ b2,
                               const int* __restrict__ dlist, const int* __restrict__ dcountp,
                               unsigned short* __restrict__ Out, int ndst, int do_lrelu)
{
    int nd = dcountp ? dcountp[0] : ndst;
    int lane = threadIdx.x & 63;
    int head = lane >> 4;      // 128 cols per head = 16 lanes * 8
    int col = lane * 8;
    for (int i = blockIdx.x * 4 + (threadIdx.x >> 6); i < nd; i += gridDim.x * 4) {
        int d = dlist ? dlist[i] : i;
        float r[8], acc[8];
        // ---- edge type 1: heads 0-3, H cols [0,512) ----
        {
            int beg = rowptrc[d], end = rowptrc[d + 1];
            float ad = adst[(size_t)d * 8 + head];
            float den = 0.f;
#pragma unroll
            for (int k = 0; k < 8; k++) acc[k] = 0.f;
            for (int j = beg; j < end; j++) {
                int s = srcsc[j];
                float v = asrc[(size_t)s * 8 + head] + ad;
                v = v > 0.f ? v : 0.2f * v;
                float ex = expf(v);
                den += ex;
                short8 hv = *(const short8*)(H + (size_t)s * 1024 + col);
#pragma unroll
                for (int k = 0; k < 8; k++) acc[k] += ex * bf2f((unsigned short)hv[k]);
            }
            float inv = den > 0.f ? 1.f / den : 0.f;
#pragma unroll
            for (int k = 0; k < 8; k++) r[k] = acc[k] * inv;
        }
        // ---- edge type 2: heads 4-7, H cols [512,1024) ----
        {
            int beg = rowptrc[N_NODES + d], end = rowptrc[N_NODES + d + 1];
            float ad = adst[(size_t)d * 8 + 4 + head];
            float den = 0.f;
#pragma unroll
            for (int k = 0; k < 8; k++) acc[k] = 0.f;
            for (int j = beg; j < end; j++) {
                int s = srcsc[j];
                float v = asrc[(size_t)s * 8 + 4 + head] + ad;
                v = v > 0.f ? v : 0.2f * v;
                float ex = expf(v);
                den += ex;
                short8 hv = *(const short8*)(H + (size_t)s * 1024 + 512 + col);
#pragma unroll
                for (int k = 0; k < 8; k++) acc[k] += ex * bf2f((unsigned short)hv[k]);
            }
            float inv = den > 0.f ? 1.f / den : 0.f;
#pragma unroll
            for (int k = 0; k < 8; k++) r[k] += acc[k] * inv;
        }
        short8 o;
#pragma unroll
        for (int k = 0; k < 8; k++) {
            float f = r[k] + b1[col + k] + b2[col + k];
            if (do_lrelu) f = f > 0.f ? f : 0.01f * f;
            o[k] = (short)f2bf(f);
        }
        *(short8*)(Out + (size_t)i * 512 + col) = o;
    }
}

extern "C" void kernel_launch(void* const* d_in, const int* in_sizes, int n_in,
                              void* d_out, int out_size, void* d_ws, size_t ws_size,
                              hipStream_t stream)
{
    const float* x    = (const float*)d_in[0];
    const int* e1s    = (const int*)d_in[1];
    const int* e1d    = (const int*)d_in[2];
    const int* e2s    = (const int*)d_in[3];
    const int* e2d    = (const int*)d_in[4];
    const float* w0a  = (const float*)d_in[6];
    const float* as0a = (const float*)d_in[7];
    const float* ad0a = (const float*)d_in[8];
    const float* b0a  = (const float*)d_in[9];
    const float* w0b  = (const float*)d_in[10];
    const float* as0b = (const float*)d_in[11];
    const float* ad0b = (const float*)d_in[12];
    const float* b0b  = (const float*)d_in[13];
    const float* w1a  = (const float*)d_in[14];
    const float* as1a = (const float*)d_in[15];
    const float* ad1a = (const float*)d_in[16];
    const float* b1a  = (const float*)d_in[17];
    const float* w1b  = (const float*)d_in[18];
    const float* as1b = (const float*)d_in[19];
    const float* ad1b = (const float*)d_in[20];
    const float* b1b  = (const float*)d_in[21];
    const float* linw = (const float*)d_in[22];
    const float* linb = (const float*)d_in[23];
    float* out = (float*)d_out;
    (void)in_sizes; (void)n_in; (void)out_size;

    char* ws = (char*)d_ws;
    size_t off = 0;
    auto carve = [&](size_t bytes) -> void* {
        void* p = ws + off; off += (bytes + 255) & ~(size_t)255; return p;
    };
    unsigned short* WT0 = (unsigned short*)carve((size_t)2 * H_FEATS * IN_FEATS * 2); // [1024][1024]
    unsigned short* WT1 = (unsigned short*)carve((size_t)2 * H_FEATS * H_FEATS * 2);  // [1024][512]
    unsigned short* WTl = (unsigned short*)carve((size_t)N_CLASSES * H_FEATS * 2);
    unsigned short* Hbf = (unsigned short*)carve((size_t)N_NODES * 1024 * 2);  // GEMM out, node-indexed
    unsigned short* H1c = (unsigned short*)carve((size_t)N_NODES * H_FEATS * 2); // F1-compact layer-0 out
    unsigned short* h2s = (unsigned short*)carve((size_t)BATCH * H_FEATS * 2);
    float* asrc = (float*)carve((size_t)N_NODES * 8 * 4);
    float* adst = (float*)carve((size_t)N_NODES * 8 * 4);
    // cnt2 and flagbuf adjacent (2N*4 = 800000 bytes = 256-aligned exactly)
    // so ONE memset covers both.
    int* cnt2    = (int*)carve((size_t)2 * N_NODES * 4);   // histogram, then cursor
    int* flagbuf = (int*)carve((size_t)2 * N_NODES * 4);   // [flag1 | flag0]
    int* rowptrc = (int*)carve((size_t)(2 * N_NODES + 1) * 4);
    int* srcsc   = (int*)carve((size_t)2 * N_EDGES * 4);
    int* partialF= (int*)carve((size_t)2 * N_NODES * 4);
    int* partialC= (int*)carve((size_t)2 * N_NODES * 4);
    int* chunkF  = (int*)carve((size_t)1024 * 4);
    int* chunkC  = (int*)carve((size_t)1024 * 4);
    int* list1   = (int*)carve((size_t)N_NODES * 4);
    int* list0   = (int*)carve((size_t)N_NODES * 4);
    int* count1  = (int*)carve(256);
    int* count0  = (int*)carve(256);
    // compact bf16 A for layer 0 (worst case all nodes): only if ws allows.
    // Decision depends only on ws_size -> identical every call (capture-safe).
    unsigned short* xc = nullptr;
    {
        size_t need = (size_t)N_NODES * IN_FEATS * 2;
        if (off + need <= ws_size) xc = (unsigned short*)carve(need);
    }

    const int MT8 = (((N_NODES + 127) / 128) + 7) & ~7;   // 784, multiple of 8 for swizzle
    const int EG = (N_EDGES + 255) / 256;                 // 782

    // 1. zero cnt2 + flagbuf in one fill (adjacent carves)
    hipMemsetAsync(cnt2, 0, (size_t)4 * N_NODES * 4, stream);
    // 2. transposes + mark1 + hist2
    prep1_kernel<<<2048, 256, 0, stream>>>(w0a, w0b, w1a, w1b, linw, WT0, WT1, WTl,
                                           e1s, e1d, e2s, e2d, flagbuf, cnt2);
    // 3. F0 marking (needs flag1)
    mark0_kernel<<<EG, 256, 0, stream>>>(e1s, e1d, e2s, e2d, flagbuf, flagbuf + N_NODES,
                                         N_EDGES, N_NODES);
    // 4-6. dual scan chain + finalize (lists/counts + rowptr/cursor)
    scanA_kernel<<<2 * NCHUNK2, 256, 0, stream>>>(flagbuf, cnt2, partialF, chunkF, partialC, chunkC);
    scanB_kernel<<<1, 1024, 0, stream>>>(chunkF, chunkC, NCHUNK2);
    finalize_kernel<<<NCHUNK2, 256, 0, stream>>>(flagbuf, partialF, chunkF, partialC, chunkC,
                                                 list1, list0, count1, count0, rowptrc, cnt2);
    // 7. CSR fill + compact x->bf16
    fill_cvt_kernel<<<1024, 256, 0, stream>>>(e1s, e1d, e2s, e2d, cnt2, srcsc,
                                              x, list0, count0, xc ? xc : (unsigned short*)Hbf);

    // 8. layer 0: fused N=1024 GEMM over F0 rows
    if (xc) {
        gemm_kernel<<<MT8 * 8, 256, 0, stream>>>(xc, 0, 1, WT0, Hbf, nullptr,
                                                 as0a, ad0a, as0b, ad0b, asrc, adst,
                                                 list0, count0,
                                                 N_NODES, 1024, 8, IN_FEATS, 1);
    } else {
        gemm_kernel<<<MT8 * 8, 256, 0, stream>>>(x, 1, 0, WT0, Hbf, nullptr,
                                                 as0a, ad0a, as0b, ad0b, asrc, adst,
                                                 list0, count0,
                                                 N_NODES, 1024, 8, IN_FEATS, 1);
    }
    // 9. gather over F1 dsts -> H1c (compact)
    gather2_kernel<<<2048, 256, 0, stream>>>(rowptrc, srcsc, asrc, adst, Hbf, b0a, b0b,
                                             list1, count1, H1c, N_NODES, 1);
    // 10. layer 1: compact GEMM over F1 rows (scatter into Hbf)
    gemm_kernel<<<MT8 * 8, 256, 0, stream>>>(H1c, 0, 1, WT1, Hbf, nullptr,
                                             as1a, ad1a, as1b, ad1b, asrc, adst,
                                             list1, count1,
                                             N_NODES, 1024, 8, H_FEATS, 1);
    // 11. gather over BATCH dsts -> h2s
    gather2_kernel<<<256, 256, 0, stream>>>(rowptrc, srcsc, asrc, adst, Hbf, b1a, b1b,
                                            nullptr, nullptr, h2s, BATCH, 0);
    // 12. classification head
    const int HN_T = (N_CLASSES + 127) / 128;   // 24
    gemm_kernel<<<(BATCH / 128) * HN_T, 256, 0, stream>>>(h2s, 0, 0, WTl, out, linb,
                                                          nullptr, nullptr, nullptr, nullptr,
                                                          nullptr, nullptr, nullptr, nullptr,
                                                          BATCH, N_CLASSES, HN_T, H_FEATS, 0);
}